// Round 1
// baseline (1592.022 us; speedup 1.0000x reference)
//
#include <hip/hip_runtime.h>
#include <math.h>

#define PI_F 3.14159265358979323846f

// ---------------------------------------------------------------- k_stats
__global__ __launch_bounds__(256) void k_stats(const float* __restrict__ x,
                                               float* __restrict__ stats) {
    int img = blockIdx.x;                       // 4096 images
    const float* p = x + (size_t)img * 4096;
    float s = 0.f;
    for (int i = threadIdx.x; i < 1024; i += 256) {
        float4 v = ((const float4*)p)[i];
        s += v.x + v.y + v.z + v.w;
    }
    __shared__ float red[256];
    red[threadIdx.x] = s;
    __syncthreads();
    for (int off = 128; off > 0; off >>= 1) {
        if (threadIdx.x < off) red[threadIdx.x] += red[threadIdx.x + off];
        __syncthreads();
    }
    if (threadIdx.x == 0) stats[img] = red[0] * (1.0f / 4096.0f);
}

// ---------------------------------------------------------------- k_params
// idx = bt*128 + c ; computes A[idx], Xterm[idx]
__global__ __launch_bounds__(256) void k_params(const float* __restrict__ stats,
                                                const float* __restrict__ gw,
                                                const float* __restrict__ gb,
                                                const float* __restrict__ dts,
                                                float2* __restrict__ A,
                                                float2* __restrict__ Xt) {
    int idx = blockIdx.x * 256 + threadIdx.x;   // 0..4095
    int c = idx & 127;
    int bt = idx >> 7;
    const float* st = stats + bt * 128;
    float nu = gb[c], om = gb[c + 128];
    for (int k = 0; k < 128; ++k) {
        float s = st[k];
        nu += s * gw[k * 256 + c];
        om += s * gw[k * 256 + c + 128];
    }
    float dt = dts[bt];
    float lre = -fabsf(nu);
    float lim = om;
    float mag = sqrtf(lre * lre + lim * lim);
    float er = expf(lre * dt);
    float sn, cs;
    sincosf(lim * dt, &sn, &cs);
    float2 Av = make_float2(er * cs, er * sn);
    float2 X;
    if (mag < 1e-6f) {
        X = make_float2(dt, 0.f);
    } else {
        float ar = Av.x - 1.f, ai = Av.y;
        float inv = 1.f / (mag * mag);
        X = make_float2((ar * lre + ai * lim) * inv, (ai * lre - ar * lim) * inv);
    }
    A[idx] = Av;
    Xt[idx] = X;
}

// ---------------------------------------------------------------- k_rfft2
// Per-image 64x64 real 2D FFT (ortho), optional fused multiply by Xterm[img].
// Output layout: S[img][ky(64)][kx(33)] as float2.
__global__ __launch_bounds__(256) void k_rfft2(const float* __restrict__ xin,
                                               float2* __restrict__ Sout,
                                               const float2* __restrict__ Xterm,
                                               int use_xterm) {
    int img = blockIdx.x;
    int tid = threadIdx.x;
    __shared__ __align__(16) float sx[64 * 65];   // padded rows (bank-conflict-free)
    __shared__ __align__(16) float2 sR[64 * 33];

    const float* xp = xin + (size_t)img * 4096;
    for (int i = tid; i < 4096; i += 256) sx[(i >> 6) * 65 + (i & 63)] = xp[i];
    __syncthreads();

    // Stage 1: row DFTs. R[r][k] = sum_w x[r][w] e^{-2pi i k w/64}
    {
        int r = tid >> 2;
        int k0 = (tid & 3) * 9;                    // lane3 computes k up to 35, stores <33
        float ar[9], ai[9], cr[9], ci[9], wr[9], wi[9];
#pragma unroll
        for (int j = 0; j < 9; ++j) {
            float sn, cs;
            sincosf(-PI_F * (float)(k0 + j) * (1.0f / 32.0f), &sn, &cs);
            wr[j] = cs; wi[j] = sn;
            cr[j] = 1.f; ci[j] = 0.f;
            ar[j] = 0.f; ai[j] = 0.f;
        }
        const float* row = sx + r * 65;
        for (int w = 0; w < 64; ++w) {
            float xv = row[w];
#pragma unroll
            for (int j = 0; j < 9; ++j) {
                ar[j] += xv * cr[j];
                ai[j] += xv * ci[j];
                float t = cr[j] * wr[j] - ci[j] * wi[j];
                ci[j] = cr[j] * wi[j] + ci[j] * wr[j];
                cr[j] = t;
            }
        }
#pragma unroll
        for (int j = 0; j < 9; ++j) {
            int k = k0 + j;
            if (k < 33) sR[r * 33 + k] = make_float2(ar[j], ai[j]);
        }
    }
    __syncthreads();

    // Stage 2: column DFTs. F[ky][k] = sum_r R[r][k] e^{-2pi i ky r/64}
    float fr[8], fi[8], xr_[8], xi_[8];
    int k = tid >> 3;
    int ky0 = (tid & 7) * 8;
    {
        float cr[8], ci[8], wr[8], wi[8];
#pragma unroll
        for (int j = 0; j < 8; ++j) {
            float sn, cs;
            sincosf(-PI_F * (float)(ky0 + j) * (1.0f / 32.0f), &sn, &cs);
            wr[j] = cs; wi[j] = sn;
            cr[j] = 1.f; ci[j] = 0.f; fr[j] = 0.f; fi[j] = 0.f;
        }
        for (int r = 0; r < 64; ++r) {
            float2 g = sR[r * 33 + k];
#pragma unroll
            for (int j = 0; j < 8; ++j) {
                fr[j] += g.x * cr[j] - g.y * ci[j];
                fi[j] += g.x * ci[j] + g.y * cr[j];
                float t = cr[j] * wr[j] - ci[j] * wi[j];
                ci[j] = cr[j] * wi[j] + ci[j] * wr[j];
                cr[j] = t;
            }
        }
    }
    if (tid < 8) {   // extra column k=32, ky block = tid*8
        int kb0 = tid * 8;
        float cr[8], ci[8], wr[8], wi[8];
#pragma unroll
        for (int j = 0; j < 8; ++j) {
            float sn, cs;
            sincosf(-PI_F * (float)(kb0 + j) * (1.0f / 32.0f), &sn, &cs);
            wr[j] = cs; wi[j] = sn;
            cr[j] = 1.f; ci[j] = 0.f; xr_[j] = 0.f; xi_[j] = 0.f;
        }
        for (int r = 0; r < 64; ++r) {
            float2 g = sR[r * 33 + 32];
#pragma unroll
            for (int j = 0; j < 8; ++j) {
                xr_[j] += g.x * cr[j] - g.y * ci[j];
                xi_[j] += g.x * ci[j] + g.y * cr[j];
                float t = cr[j] * wr[j] - ci[j] * wi[j];
                ci[j] = cr[j] * wi[j] + ci[j] * wr[j];
                cr[j] = t;
            }
        }
    }
    __syncthreads();
#pragma unroll
    for (int j = 0; j < 8; ++j) sR[(ky0 + j) * 33 + k] = make_float2(fr[j], fi[j]);
    if (tid < 8) {
#pragma unroll
        for (int j = 0; j < 8; ++j) sR[(tid * 8 + j) * 33 + 32] = make_float2(xr_[j], xi_[j]);
    }
    __syncthreads();

    // epilogue: ortho scale (1/64), optional Xterm multiply, coalesced store
    float2 xt = make_float2(1.f, 0.f);
    if (use_xterm) xt = Xterm[img];
    float2* op = Sout + (size_t)img * 2112;
    for (int i = tid; i < 2112; i += 256) {
        float2 v = sR[i];
        v.x *= (1.0f / 64.0f);
        v.y *= (1.0f / 64.0f);
        op[i] = make_float2(v.x * xt.x - v.y * xt.y, v.x * xt.y + v.y * xt.x);
    }
}

// ---------------------------------------------------------------- k_scan
// In-place diagonal recurrence over T=16 in spectral domain.
__global__ __launch_bounds__(256) void k_scan(float2* __restrict__ S,
                                              const float2* __restrict__ A) {
    int tid = blockIdx.x * 256 + threadIdx.x;   // 2*128*2112 = 540672 exact
    int spec = tid % 2112;
    int c = (tid / 2112) & 127;
    int b = tid / (2112 * 128);
    float2 h = make_float2(0.f, 0.f);
    for (int t = 0; t < 16; ++t) {
        int bt = b * 16 + t;
        float2 a = A[bt * 128 + c];
        size_t off = ((size_t)(bt * 128 + c)) * 2112 + spec;
        float2 x = S[off];
        float hr = a.x * h.x - a.y * h.y + x.x;
        float hi = a.x * h.y + a.y * h.x + x.y;
        h = make_float2(hr, hi);
        S[off] = h;
    }
}

// ---------------------------------------------------------------- k_irfft2
// Per-image inverse of k_rfft2 (ortho). Input S[img][ky][kx], output real image.
__global__ __launch_bounds__(256) void k_irfft2(const float2* __restrict__ Sin,
                                                float* __restrict__ xout) {
    int img = blockIdx.x;
    int tid = threadIdx.x;
    __shared__ __align__(16) float2 sG[2112];
    const float2* ip = Sin + (size_t)img * 2112;
    for (int i = tid; i < 1056; i += 256) ((float4*)sG)[i] = ((const float4*)ip)[i];
    __syncthreads();

    // Stage 1: T[h][k] = sum_ky G[ky][k] e^{+2pi i ky h/64}
    float tr[8], ti[8], er_[8], ei_[8];
    int k = tid >> 3;
    int h0 = (tid & 7) * 8;
    {
        float cr[8], ci[8], wr[8], wi[8];
#pragma unroll
        for (int j = 0; j < 8; ++j) {
            float sn, cs;
            sincosf(PI_F * (float)(h0 + j) * (1.0f / 32.0f), &sn, &cs);
            wr[j] = cs; wi[j] = sn;
            cr[j] = 1.f; ci[j] = 0.f; tr[j] = 0.f; ti[j] = 0.f;
        }
        for (int ky = 0; ky < 64; ++ky) {
            float2 g = sG[ky * 33 + k];
#pragma unroll
            for (int j = 0; j < 8; ++j) {
                tr[j] += g.x * cr[j] - g.y * ci[j];
                ti[j] += g.x * ci[j] + g.y * cr[j];
                float t = cr[j] * wr[j] - ci[j] * wi[j];
                ci[j] = cr[j] * wi[j] + ci[j] * wr[j];
                cr[j] = t;
            }
        }
    }
    if (tid < 8) {    // k = 32 column
        int hb0 = tid * 8;
        float cr[8], ci[8], wr[8], wi[8];
#pragma unroll
        for (int j = 0; j < 8; ++j) {
            float sn, cs;
            sincosf(PI_F * (float)(hb0 + j) * (1.0f / 32.0f), &sn, &cs);
            wr[j] = cs; wi[j] = sn;
            cr[j] = 1.f; ci[j] = 0.f; er_[j] = 0.f; ei_[j] = 0.f;
        }
        for (int ky = 0; ky < 64; ++ky) {
            float2 g = sG[ky * 33 + 32];
#pragma unroll
            for (int j = 0; j < 8; ++j) {
                er_[j] += g.x * cr[j] - g.y * ci[j];
                ei_[j] += g.x * ci[j] + g.y * cr[j];
                float t = cr[j] * wr[j] - ci[j] * wi[j];
                ci[j] = cr[j] * wi[j] + ci[j] * wr[j];
                cr[j] = t;
            }
        }
    }
    __syncthreads();
#pragma unroll
    for (int j = 0; j < 8; ++j) sG[(h0 + j) * 33 + k] = make_float2(tr[j], ti[j]);
    if (tid < 8) {
#pragma unroll
        for (int j = 0; j < 8; ++j) sG[(tid * 8 + j) * 33 + 32] = make_float2(er_[j], ei_[j]);
    }
    __syncthreads();

    // Stage 2: rows via Hermitian symmetry in kx.
    float res[16];
    {
        int h = tid >> 2;
        int w0 = (tid & 3) * 16;
        float t0 = sG[h * 33 + 0].x;
        float t32 = sG[h * 33 + 32].x;
        float cr[16], ci[16], wr[16], wi[16];
#pragma unroll
        for (int j = 0; j < 16; ++j) {
            float sn, cs;
            sincosf(PI_F * (float)(w0 + j) * (1.0f / 32.0f), &sn, &cs);
            wr[j] = cs; wi[j] = sn;
            cr[j] = cs; ci[j] = sn;                 // value at k=1
            res[j] = t0 + (((w0 + j) & 1) ? -t32 : t32);
        }
        for (int kk = 1; kk < 32; ++kk) {
            float2 g = sG[h * 33 + kk];
#pragma unroll
            for (int j = 0; j < 16; ++j) {
                res[j] += 2.0f * (g.x * cr[j] - g.y * ci[j]);
                float t = cr[j] * wr[j] - ci[j] * wi[j];
                ci[j] = cr[j] * wi[j] + ci[j] * wr[j];
                cr[j] = t;
            }
        }
    }
    __syncthreads();
    float* sf = (float*)sG;
    {
        int h = tid >> 2;
        int w0 = (tid & 3) * 16;
#pragma unroll
        for (int j = 0; j < 16; ++j) sf[h * 64 + w0 + j] = res[j] * (1.0f / 64.0f);
    }
    __syncthreads();
    float* op = xout + (size_t)img * 4096;
    for (int i = tid; i < 1024; i += 256) ((float4*)op)[i] = ((const float4*)sf)[i];
}

// ---------------------------------------------------------------- k_conv
// u = h + clifford_conv(h).  Per block: 8 output channels x (8 rows x 64 cols).
__global__ __launch_bounds__(256) void k_conv(const float* __restrict__ hin,
                                              const float* __restrict__ cwa,
                                              const float* __restrict__ cwb,
                                              const float* __restrict__ cba,
                                              const float* __restrict__ cbb,
                                              float* __restrict__ uout) {
    int r0 = blockIdx.x * 8;     // row tile
    int co0 = blockIdx.y * 8;    // out-channel tile
    int f = blockIdx.z;          // frame
    __shared__ float sa[10][66];
    __shared__ float sb[10][66];
    int tid = threadIdx.x;
    int lrow = tid >> 6;         // 0..3
    int lcol = tid & 63;
    float acc_a[2][8], acc_b[2][8];
#pragma unroll
    for (int p = 0; p < 2; ++p)
#pragma unroll
        for (int co = 0; co < 8; ++co) { acc_a[p][co] = 0.f; acc_b[p][co] = 0.f; }

    const float* base = hin + (size_t)f * 128 * 4096;
    for (int ci = 0; ci < 64; ++ci) {
        const float* ap = base + ci * 4096;
        const float* bp = base + (ci + 64) * 4096;
        for (int i = tid; i < 660; i += 256) {
            int hr = i / 66, hc = i - hr * 66;
            int gr = r0 + hr - 1, gc = hc - 1;
            bool ok = (gr >= 0) && (gr < 64) && (gc >= 0) && (gc < 64);
            sa[hr][hc] = ok ? ap[gr * 64 + gc] : 0.f;
            sb[hr][hc] = ok ? bp[gr * 64 + gc] : 0.f;
        }
        __syncthreads();

        float at0[2][9], bt0[2][9];
#pragma unroll
        for (int p = 0; p < 2; ++p) {
            int row = lrow + p * 4;
#pragma unroll
            for (int dr = 0; dr < 3; ++dr)
#pragma unroll
                for (int dc = 0; dc < 3; ++dc) {
                    at0[p][dr * 3 + dc] = sa[row + dr][lcol + dc];
                    bt0[p][dr * 3 + dc] = sb[row + dr][lcol + dc];
                }
        }
#pragma unroll
        for (int co = 0; co < 8; ++co) {
            const float* wap = cwa + ((size_t)(co0 + co) * 64 + ci) * 9;
            const float* wbp = cwb + ((size_t)(co0 + co) * 64 + ci) * 9;
#pragma unroll
            for (int t = 0; t < 9; ++t) {
                float wa = wap[t], wb = wbp[t];
#pragma unroll
                for (int p = 0; p < 2; ++p) {
                    acc_a[p][co] += at0[p][t] * wa - bt0[p][t] * wb;
                    acc_b[p][co] += at0[p][t] * wb + bt0[p][t] * wa;
                }
            }
        }
        __syncthreads();
    }
#pragma unroll
    for (int p = 0; p < 2; ++p) {
        int grow = r0 + lrow + p * 4;
#pragma unroll
        for (int co = 0; co < 8; ++co) {
            int ca = co0 + co;
            size_t ia = ((size_t)f * 128 + ca) * 4096 + grow * 64 + lcol;
            size_t ib = ((size_t)f * 128 + 64 + ca) * 4096 + grow * 64 + lcol;
            uout[ia] = hin[ia] + acc_a[p][co] + cba[ca];
            uout[ib] = hin[ib] + acc_b[p][co] + cbb[ca];
        }
    }
}

// ---------------------------------------------------------------- k_project
// Helmholtz projection in spectral domain, in-place.
__global__ __launch_bounds__(256) void k_project(float2* __restrict__ S) {
    int tid = blockIdx.x * 256 + threadIdx.x;   // 32*64*2112 exact
    int spec = tid % 2112;
    int rest = tid / 2112;
    int ch = rest & 63;
    int f = rest >> 6;
    int kyi = spec / 33;
    int kxi = spec - kyi * 33;
    float kx = (float)kxi * (1.0f / 64.0f);
    float kyv = (float)(kyi < 32 ? kyi : kyi - 64) * (1.0f / 64.0f);
    float k2 = kx * kx + kyv * kyv;
    if (k2 > 0.f) {
        size_t ix = ((size_t)(f * 128 + ch)) * 2112 + spec;
        size_t iy = ((size_t)(f * 128 + 64 + ch)) * 2112 + spec;
        float2 vx = S[ix], vy = S[iy];
        float inv = 1.0f / k2;
        float pr = (kx * vx.x + kyv * vy.x) * inv;
        float pi = (kx * vx.y + kyv * vy.y) * inv;
        S[ix] = make_float2(vx.x - kx * pr, vx.y - kx * pi);
        S[iy] = make_float2(vy.x - kyv * pr, vy.y - kyv * pi);
    }
}

// ---------------------------------------------------------------- group norm
__global__ __launch_bounds__(1024) void k_gnstats(const float* __restrict__ u,
                                                  float2* __restrict__ gs) {
    int f = blockIdx.x >> 2, g = blockIdx.x & 3;
    const float* p = u + ((size_t)f * 128 + g * 32) * 4096;
    float s = 0.f, s2 = 0.f;
    for (int i = threadIdx.x; i < 32768; i += 1024) {
        float4 v = ((const float4*)p)[i];
        s += v.x + v.y + v.z + v.w;
        s2 += v.x * v.x + v.y * v.y + v.z * v.z + v.w * v.w;
    }
    __shared__ float rs[1024], rq[1024];
    rs[threadIdx.x] = s; rq[threadIdx.x] = s2;
    __syncthreads();
    for (int off = 512; off > 0; off >>= 1) {
        if (threadIdx.x < off) {
            rs[threadIdx.x] += rs[threadIdx.x + off];
            rq[threadIdx.x] += rq[threadIdx.x + off];
        }
        __syncthreads();
    }
    if (threadIdx.x == 0) {
        float mu = rs[0] * (1.0f / 131072.0f);
        float var = rq[0] * (1.0f / 131072.0f) - mu * mu;
        gs[blockIdx.x] = make_float2(mu, rsqrtf(var + 1e-5f));
    }
}

__global__ __launch_bounds__(256) void k_gnapply(const float* __restrict__ u,
                                                 const float2* __restrict__ gs,
                                                 const float* __restrict__ gnw,
                                                 const float* __restrict__ gnb,
                                                 float* __restrict__ out) {
    size_t i4 = (size_t)blockIdx.x * 256 + threadIdx.x;   // 4194304 exact
    size_t i = i4 * 4;
    float4 v = ((const float4*)u)[i4];
    int cl = (int)(i >> 12);      // f*128 + c
    int c = cl & 127;
    int fg = cl >> 5;             // f*4 + g
    float2 ms = gs[fg];
    float sc = ms.y * gnw[c];
    float sh = gnb[c] - ms.x * sc;
    float4 r;
    r.x = v.x * sc + sh; r.y = v.y * sc + sh;
    r.z = v.z * sc + sh; r.w = v.w * sc + sh;
    ((float4*)out)[i4] = r;
}

// ---------------------------------------------------------------- launch
extern "C" void kernel_launch(void* const* d_in, const int* in_sizes, int n_in,
                              void* d_out, int out_size, void* d_ws, size_t ws_size,
                              hipStream_t stream) {
    (void)in_sizes; (void)n_in; (void)out_size; (void)ws_size;
    const float* x   = (const float*)d_in[0];
    const float* dts = (const float*)d_in[1];
    const float* gw  = (const float*)d_in[2];
    const float* gb  = (const float*)d_in[3];
    const float* cwa = (const float*)d_in[4];
    const float* cwb = (const float*)d_in[5];
    const float* cba = (const float*)d_in[6];
    const float* cbb = (const float*)d_in[7];
    const float* gnw = (const float*)d_in[8];
    const float* gnb = (const float*)d_in[9];
    float* out = (float*)d_out;
    char* ws = (char*)d_ws;

    float2* S     = (float2*)ws;                        // 4096*2112*8 = 69,206,016 B
    float*  H1    = (float*)(ws + 69206016);            // 67,108,864 B
    float*  stats = (float*)(ws + 136314880);           // 16,384 B
    float2* A     = (float2*)(ws + 136331264);          // 32,768 B
    float2* Xt    = (float2*)(ws + 136364032);          // 32,768 B
    float2* gs    = (float2*)(ws + 136396800);          // 1,024 B

    k_stats<<<4096, 256, 0, stream>>>(x, stats);
    k_params<<<16, 256, 0, stream>>>(stats, gw, gb, dts, A, Xt);
    k_rfft2<<<4096, 256, 0, stream>>>(x, S, Xt, 1);
    k_scan<<<2112, 256, 0, stream>>>(S, A);
    k_irfft2<<<4096, 256, 0, stream>>>(S, H1);
    k_conv<<<dim3(8, 8, 32), 256, 0, stream>>>(H1, cwa, cwb, cba, cbb, out);
    k_rfft2<<<4096, 256, 0, stream>>>(out, S, Xt, 0);
    k_project<<<16896, 256, 0, stream>>>(S);
    k_irfft2<<<4096, 256, 0, stream>>>(S, H1);
    k_gnstats<<<128, 1024, 0, stream>>>(H1, gs);
    k_gnapply<<<16384, 256, 0, stream>>>(H1, gs, gnw, gnb, out);
}

// Round 2
// 1109.622 us; speedup vs baseline: 1.4347x; 1.4347x over previous
//
#include <hip/hip_runtime.h>
#include <math.h>

#define PI_F 3.14159265358979323846f

typedef __attribute__((ext_vector_type(8))) short short8;
typedef __attribute__((ext_vector_type(4))) float f32x4;

static __device__ __forceinline__ unsigned short f2bf(float x) {
    unsigned u = __float_as_uint(x);
    unsigned r = (u + 0x7FFF + ((u >> 16) & 1)) >> 16;
    return (unsigned short)r;
}

// ---------------------------------------------------------------- k_stats
__global__ __launch_bounds__(256) void k_stats(const float* __restrict__ x,
                                               float* __restrict__ stats) {
    int img = blockIdx.x;                       // 4096 images
    const float* p = x + (size_t)img * 4096;
    float s = 0.f;
    for (int i = threadIdx.x; i < 1024; i += 256) {
        float4 v = ((const float4*)p)[i];
        s += v.x + v.y + v.z + v.w;
    }
    __shared__ float red[256];
    red[threadIdx.x] = s;
    __syncthreads();
    for (int off = 128; off > 0; off >>= 1) {
        if (threadIdx.x < off) red[threadIdx.x] += red[threadIdx.x + off];
        __syncthreads();
    }
    if (threadIdx.x == 0) stats[img] = red[0] * (1.0f / 4096.0f);
}

// ---------------------------------------------------------------- k_params
__global__ __launch_bounds__(256) void k_params(const float* __restrict__ stats,
                                                const float* __restrict__ gw,
                                                const float* __restrict__ gb,
                                                const float* __restrict__ dts,
                                                float2* __restrict__ A,
                                                float2* __restrict__ Xt) {
    int idx = blockIdx.x * 256 + threadIdx.x;   // 0..4095
    int c = idx & 127;
    int bt = idx >> 7;
    const float* st = stats + bt * 128;
    float nu = gb[c], om = gb[c + 128];
    for (int k = 0; k < 128; ++k) {
        float s = st[k];
        nu += s * gw[k * 256 + c];
        om += s * gw[k * 256 + c + 128];
    }
    float dt = dts[bt];
    float lre = -fabsf(nu);
    float lim = om;
    float mag = sqrtf(lre * lre + lim * lim);
    float er = expf(lre * dt);
    float sn, cs;
    sincosf(lim * dt, &sn, &cs);
    float2 Av = make_float2(er * cs, er * sn);
    float2 X;
    if (mag < 1e-6f) {
        X = make_float2(dt, 0.f);
    } else {
        float ar = Av.x - 1.f, ai = Av.y;
        float inv = 1.f / (mag * mag);
        X = make_float2((ar * lre + ai * lim) * inv, (ai * lre - ar * lim) * inv);
    }
    A[idx] = Av;
    Xt[idx] = X;
}

// ---------------------------------------------------------------- k_rfft2
__global__ __launch_bounds__(256) void k_rfft2(const float* __restrict__ xin,
                                               float2* __restrict__ Sout,
                                               const float2* __restrict__ Xterm,
                                               int use_xterm) {
    int img = blockIdx.x;
    int tid = threadIdx.x;
    __shared__ __align__(16) float sx[64 * 65];
    __shared__ __align__(16) float2 sR[64 * 33];

    const float* xp = xin + (size_t)img * 4096;
    for (int i = tid; i < 4096; i += 256) sx[(i >> 6) * 65 + (i & 63)] = xp[i];
    __syncthreads();

    // Stage 1: row DFTs
    {
        int r = tid >> 2;
        int k0 = (tid & 3) * 9;
        float ar[9], ai[9], cr[9], ci[9], wr[9], wi[9];
#pragma unroll
        for (int j = 0; j < 9; ++j) {
            float sn, cs;
            sincosf(-PI_F * (float)(k0 + j) * (1.0f / 32.0f), &sn, &cs);
            wr[j] = cs; wi[j] = sn;
            cr[j] = 1.f; ci[j] = 0.f;
            ar[j] = 0.f; ai[j] = 0.f;
        }
        const float* row = sx + r * 65;
        for (int w = 0; w < 64; ++w) {
            float xv = row[w];
#pragma unroll
            for (int j = 0; j < 9; ++j) {
                ar[j] += xv * cr[j];
                ai[j] += xv * ci[j];
                float t = cr[j] * wr[j] - ci[j] * wi[j];
                ci[j] = cr[j] * wi[j] + ci[j] * wr[j];
                cr[j] = t;
            }
        }
#pragma unroll
        for (int j = 0; j < 9; ++j) {
            int k = k0 + j;
            if (k < 33) sR[r * 33 + k] = make_float2(ar[j], ai[j]);
        }
    }
    __syncthreads();

    // Stage 2: column DFTs
    float fr[8], fi[8], xr_[8], xi_[8];
    int k = tid >> 3;
    int ky0 = (tid & 7) * 8;
    {
        float cr[8], ci[8], wr[8], wi[8];
#pragma unroll
        for (int j = 0; j < 8; ++j) {
            float sn, cs;
            sincosf(-PI_F * (float)(ky0 + j) * (1.0f / 32.0f), &sn, &cs);
            wr[j] = cs; wi[j] = sn;
            cr[j] = 1.f; ci[j] = 0.f; fr[j] = 0.f; fi[j] = 0.f;
        }
        for (int r = 0; r < 64; ++r) {
            float2 g = sR[r * 33 + k];
#pragma unroll
            for (int j = 0; j < 8; ++j) {
                fr[j] += g.x * cr[j] - g.y * ci[j];
                fi[j] += g.x * ci[j] + g.y * cr[j];
                float t = cr[j] * wr[j] - ci[j] * wi[j];
                ci[j] = cr[j] * wi[j] + ci[j] * wr[j];
                cr[j] = t;
            }
        }
    }
    if (tid < 8) {
        int kb0 = tid * 8;
        float cr[8], ci[8], wr[8], wi[8];
#pragma unroll
        for (int j = 0; j < 8; ++j) {
            float sn, cs;
            sincosf(-PI_F * (float)(kb0 + j) * (1.0f / 32.0f), &sn, &cs);
            wr[j] = cs; wi[j] = sn;
            cr[j] = 1.f; ci[j] = 0.f; xr_[j] = 0.f; xi_[j] = 0.f;
        }
        for (int r = 0; r < 64; ++r) {
            float2 g = sR[r * 33 + 32];
#pragma unroll
            for (int j = 0; j < 8; ++j) {
                xr_[j] += g.x * cr[j] - g.y * ci[j];
                xi_[j] += g.x * ci[j] + g.y * cr[j];
                float t = cr[j] * wr[j] - ci[j] * wi[j];
                ci[j] = cr[j] * wi[j] + ci[j] * wr[j];
                cr[j] = t;
            }
        }
    }
    __syncthreads();
#pragma unroll
    for (int j = 0; j < 8; ++j) sR[(ky0 + j) * 33 + k] = make_float2(fr[j], fi[j]);
    if (tid < 8) {
#pragma unroll
        for (int j = 0; j < 8; ++j) sR[(tid * 8 + j) * 33 + 32] = make_float2(xr_[j], xi_[j]);
    }
    __syncthreads();

    float2 xt = make_float2(1.f, 0.f);
    if (use_xterm) xt = Xterm[img];
    float2* op = Sout + (size_t)img * 2112;
    for (int i = tid; i < 2112; i += 256) {
        float2 v = sR[i];
        v.x *= (1.0f / 64.0f);
        v.y *= (1.0f / 64.0f);
        op[i] = make_float2(v.x * xt.x - v.y * xt.y, v.x * xt.y + v.y * xt.x);
    }
}

// ---------------------------------------------------------------- k_scan
__global__ __launch_bounds__(256) void k_scan(float2* __restrict__ S,
                                              const float2* __restrict__ A) {
    int tid = blockIdx.x * 256 + threadIdx.x;
    int spec = tid % 2112;
    int c = (tid / 2112) & 127;
    int b = tid / (2112 * 128);
    float2 h = make_float2(0.f, 0.f);
    for (int t = 0; t < 16; ++t) {
        int bt = b * 16 + t;
        float2 a = A[bt * 128 + c];
        size_t off = ((size_t)(bt * 128 + c)) * 2112 + spec;
        float2 x = S[off];
        float hr = a.x * h.x - a.y * h.y + x.x;
        float hi = a.x * h.y + a.y * h.x + x.y;
        h = make_float2(hr, hi);
        S[off] = h;
    }
}

// ---------------------------------------------------------------- k_irfft2
__global__ __launch_bounds__(256) void k_irfft2(const float2* __restrict__ Sin,
                                                float* __restrict__ xout) {
    int img = blockIdx.x;
    int tid = threadIdx.x;
    __shared__ __align__(16) float2 sG[2112];
    const float2* ip = Sin + (size_t)img * 2112;
    for (int i = tid; i < 1056; i += 256) ((float4*)sG)[i] = ((const float4*)ip)[i];
    __syncthreads();

    float tr[8], ti[8], er_[8], ei_[8];
    int k = tid >> 3;
    int h0 = (tid & 7) * 8;
    {
        float cr[8], ci[8], wr[8], wi[8];
#pragma unroll
        for (int j = 0; j < 8; ++j) {
            float sn, cs;
            sincosf(PI_F * (float)(h0 + j) * (1.0f / 32.0f), &sn, &cs);
            wr[j] = cs; wi[j] = sn;
            cr[j] = 1.f; ci[j] = 0.f; tr[j] = 0.f; ti[j] = 0.f;
        }
        for (int ky = 0; ky < 64; ++ky) {
            float2 g = sG[ky * 33 + k];
#pragma unroll
            for (int j = 0; j < 8; ++j) {
                tr[j] += g.x * cr[j] - g.y * ci[j];
                ti[j] += g.x * ci[j] + g.y * cr[j];
                float t = cr[j] * wr[j] - ci[j] * wi[j];
                ci[j] = cr[j] * wi[j] + ci[j] * wr[j];
                cr[j] = t;
            }
        }
    }
    if (tid < 8) {
        int hb0 = tid * 8;
        float cr[8], ci[8], wr[8], wi[8];
#pragma unroll
        for (int j = 0; j < 8; ++j) {
            float sn, cs;
            sincosf(PI_F * (float)(hb0 + j) * (1.0f / 32.0f), &sn, &cs);
            wr[j] = cs; wi[j] = sn;
            cr[j] = 1.f; ci[j] = 0.f; er_[j] = 0.f; ei_[j] = 0.f;
        }
        for (int ky = 0; ky < 64; ++ky) {
            float2 g = sG[ky * 33 + 32];
#pragma unroll
            for (int j = 0; j < 8; ++j) {
                er_[j] += g.x * cr[j] - g.y * ci[j];
                ei_[j] += g.x * ci[j] + g.y * cr[j];
                float t = cr[j] * wr[j] - ci[j] * wi[j];
                ci[j] = cr[j] * wi[j] + ci[j] * wr[j];
                cr[j] = t;
            }
        }
    }
    __syncthreads();
#pragma unroll
    for (int j = 0; j < 8; ++j) sG[(h0 + j) * 33 + k] = make_float2(tr[j], ti[j]);
    if (tid < 8) {
#pragma unroll
        for (int j = 0; j < 8; ++j) sG[(tid * 8 + j) * 33 + 32] = make_float2(er_[j], ei_[j]);
    }
    __syncthreads();

    float res[16];
    {
        int h = tid >> 2;
        int w0 = (tid & 3) * 16;
        float t0 = sG[h * 33 + 0].x;
        float t32 = sG[h * 33 + 32].x;
        float cr[16], ci[16], wr[16], wi[16];
#pragma unroll
        for (int j = 0; j < 16; ++j) {
            float sn, cs;
            sincosf(PI_F * (float)(w0 + j) * (1.0f / 32.0f), &sn, &cs);
            wr[j] = cs; wi[j] = sn;
            cr[j] = cs; ci[j] = sn;
            res[j] = t0 + (((w0 + j) & 1) ? -t32 : t32);
        }
        for (int kk = 1; kk < 32; ++kk) {
            float2 g = sG[h * 33 + kk];
#pragma unroll
            for (int j = 0; j < 16; ++j) {
                res[j] += 2.0f * (g.x * cr[j] - g.y * ci[j]);
                float t = cr[j] * wr[j] - ci[j] * wi[j];
                ci[j] = cr[j] * wi[j] + ci[j] * wr[j];
                cr[j] = t;
            }
        }
    }
    __syncthreads();
    float* sf = (float*)sG;
    {
        int h = tid >> 2;
        int w0 = (tid & 3) * 16;
#pragma unroll
        for (int j = 0; j < 16; ++j) sf[h * 64 + w0 + j] = res[j] * (1.0f / 64.0f);
    }
    __syncthreads();
    float* op = xout + (size_t)img * 4096;
    for (int i = tid; i < 1024; i += 256) ((float4*)op)[i] = ((const float4*)sf)[i];
}

// ---------------------------------------------------------------- k_wprep
// Expand Clifford weights (+identity at center tap) into MFMA fragment order:
// Wb[((t*4+cb)*128 + m)*32 + klocal], bf16.  m = out ch (128), ci = cb*32+klocal.
__global__ __launch_bounds__(256) void k_wprep(const float* __restrict__ cwa,
                                               const float* __restrict__ cwb,
                                               unsigned short* __restrict__ Wb) {
    int idx = blockIdx.x * 256 + threadIdx.x;   // 147456 total
    int kl = idx & 31;
    int m = (idx >> 5) & 127;
    int tcb = idx >> 12;          // 0..35
    int cb = tcb & 3, t = tcb >> 2;
    int ci = cb * 32 + kl;
    int mm = m & 63, cc = ci & 63;
    float w;
    if (m < 64) w = (ci < 64) ? cwa[(mm * 64 + cc) * 9 + t] : -cwb[(mm * 64 + cc) * 9 + t];
    else        w = (ci < 64) ? cwb[(mm * 64 + cc) * 9 + t] :  cwa[(mm * 64 + cc) * 9 + t];
    if (m == ci && t == 4) w += 1.0f;   // residual folded into center tap
    Wb[idx] = f2bf(w);
}

// ---------------------------------------------------------------- k_conv_mfma
// u = h + clifford_conv(h) via bf16 MFMA implicit GEMM.
// Block: frame f, 2 image rows (N=128 px), M=128 out ch. 4 waves in 2x2.
// LDS: 4 rows x 64 cols x 128 ci bf16, ci-inner, XOR-swizzled 16B slots (64KiB).
__global__ __launch_bounds__(256, 2) void k_conv_mfma(const float* __restrict__ hin,
                                                      const unsigned short* __restrict__ Wb,
                                                      const float* __restrict__ cba,
                                                      const float* __restrict__ cbb,
                                                      float* __restrict__ uout) {
    __shared__ __align__(16) char smem[65536];
    int f = blockIdx.y;
    int r0 = blockIdx.x * 2;
    int tid = threadIdx.x;
    const float* base = hin + (size_t)f * 524288;   // 128*4096

    // stage input tile (rows r0-1..r0+2, zero-padded), fp32 -> bf16
    for (int j = tid; j < 4096; j += 256) {
        int row = j >> 10;           // 0..3
        int cig = (j >> 6) & 15;     // group of 8 channels
        int col = j & 63;
        int gr = r0 - 1 + row;
        short8 v = (short8)0;
        if ((unsigned)gr < 64u) {
            const float* p = base + (size_t)(cig * 8) * 4096 + gr * 64 + col;
#pragma unroll
            for (int e = 0; e < 8; ++e) v[e] = (short)f2bf(p[(size_t)e * 4096]);
        }
        int byteoff = ((row * 64 + col) << 8) + ((cig ^ (col & 15)) << 4);
        *(short8*)(smem + byteoff) = v;
    }
    __syncthreads();

    int wid = tid >> 6, lane = tid & 63;
    int lhi = lane >> 4, llo = lane & 15;
    int row_off = wid & 1;            // which of the 2 output rows
    int mbase = (wid >> 1) * 64;      // out-channel half

    f32x4 acc[4][4];
#pragma unroll
    for (int mf = 0; mf < 4; ++mf)
#pragma unroll
        for (int nf = 0; nf < 4; ++nf) acc[mf][nf] = (f32x4)0.f;

    // per-nf lane columns (compile-time constant structure)
    for (int t = 0; t < 9; ++t) {
        int dy = t / 3 - 1, dx = t % 3 - 1;
        int prow = row_off + 1 + dy;                 // staged row 0..3
#pragma unroll
        for (int cb = 0; cb < 4; ++cb) {
            // A fragments (weights) from global (L2-resident)
            short8 a[4];
            const unsigned short* wp = Wb + ((size_t)((t * 4 + cb) * 128 + mbase + llo)) * 32 + lhi * 8;
#pragma unroll
            for (int mf = 0; mf < 4; ++mf) a[mf] = *(const short8*)(wp + mf * 16 * 32);
            // B fragments (im2col via shifted LDS reads)
            short8 b[4];
            int slot = cb * 4 + lhi;
#pragma unroll
            for (int nf = 0; nf < 4; ++nf) {
                int c = nf * 16 + llo;
                int cdx = c + dx;
                bool valid = ((unsigned)cdx < 64u);
                int cr = valid ? cdx : c;
                int byteoff = ((prow * 64 + cr) << 8) + ((slot ^ (cr & 15)) << 4);
                short8 bb = *(const short8*)(smem + byteoff);
                b[nf] = valid ? bb : (short8)0;
            }
#pragma unroll
            for (int mf = 0; mf < 4; ++mf)
#pragma unroll
                for (int nf = 0; nf < 4; ++nf)
                    acc[mf][nf] = __builtin_amdgcn_mfma_f32_16x16x32_bf16(a[mf], b[nf], acc[mf][nf], 0, 0, 0);
        }
    }

    // epilogue: bias + store fp32
    int grow = r0 + row_off;
#pragma unroll
    for (int mf = 0; mf < 4; ++mf) {
#pragma unroll
        for (int r = 0; r < 4; ++r) {
            int co = mbase + mf * 16 + lhi * 4 + r;
            float bias = (co < 64) ? cba[co] : cbb[co - 64];
            float* op = uout + ((size_t)f * 128 + co) * 4096 + (size_t)grow * 64;
#pragma unroll
            for (int nf = 0; nf < 4; ++nf)
                op[nf * 16 + llo] = acc[mf][nf][r] + bias;
        }
    }
}

// ---------------------------------------------------------------- k_project
__global__ __launch_bounds__(256) void k_project(float2* __restrict__ S) {
    int tid = blockIdx.x * 256 + threadIdx.x;
    int spec = tid % 2112;
    int rest = tid / 2112;
    int ch = rest & 63;
    int f = rest >> 6;
    int kyi = spec / 33;
    int kxi = spec - kyi * 33;
    float kx = (float)kxi * (1.0f / 64.0f);
    float kyv = (float)(kyi < 32 ? kyi : kyi - 64) * (1.0f / 64.0f);
    float k2 = kx * kx + kyv * kyv;
    if (k2 > 0.f) {
        size_t ix = ((size_t)(f * 128 + ch)) * 2112 + spec;
        size_t iy = ((size_t)(f * 128 + 64 + ch)) * 2112 + spec;
        float2 vx = S[ix], vy = S[iy];
        float inv = 1.0f / k2;
        float pr = (kx * vx.x + kyv * vy.x) * inv;
        float pi = (kx * vx.y + kyv * vy.y) * inv;
        S[ix] = make_float2(vx.x - kx * pr, vx.y - kx * pi);
        S[iy] = make_float2(vy.x - kyv * pr, vy.y - kyv * pi);
    }
}

// ---------------------------------------------------------------- group norm
__global__ __launch_bounds__(1024) void k_gnstats(const float* __restrict__ u,
                                                  float2* __restrict__ gs) {
    int f = blockIdx.x >> 2, g = blockIdx.x & 3;
    const float* p = u + ((size_t)f * 128 + g * 32) * 4096;
    float s = 0.f, s2 = 0.f;
    for (int i = threadIdx.x; i < 32768; i += 1024) {
        float4 v = ((const float4*)p)[i];
        s += v.x + v.y + v.z + v.w;
        s2 += v.x * v.x + v.y * v.y + v.z * v.z + v.w * v.w;
    }
    __shared__ float rs[1024], rq[1024];
    rs[threadIdx.x] = s; rq[threadIdx.x] = s2;
    __syncthreads();
    for (int off = 512; off > 0; off >>= 1) {
        if (threadIdx.x < off) {
            rs[threadIdx.x] += rs[threadIdx.x + off];
            rq[threadIdx.x] += rq[threadIdx.x + off];
        }
        __syncthreads();
    }
    if (threadIdx.x == 0) {
        float mu = rs[0] * (1.0f / 131072.0f);
        float var = rq[0] * (1.0f / 131072.0f) - mu * mu;
        gs[blockIdx.x] = make_float2(mu, rsqrtf(var + 1e-5f));
    }
}

__global__ __launch_bounds__(256) void k_gnapply(const float* __restrict__ u,
                                                 const float2* __restrict__ gs,
                                                 const float* __restrict__ gnw,
                                                 const float* __restrict__ gnb,
                                                 float* __restrict__ out) {
    size_t i4 = (size_t)blockIdx.x * 256 + threadIdx.x;
    size_t i = i4 * 4;
    float4 v = ((const float4*)u)[i4];
    int cl = (int)(i >> 12);
    int c = cl & 127;
    int fg = cl >> 5;
    float2 ms = gs[fg];
    float sc = ms.y * gnw[c];
    float sh = gnb[c] - ms.x * sc;
    float4 r;
    r.x = v.x * sc + sh; r.y = v.y * sc + sh;
    r.z = v.z * sc + sh; r.w = v.w * sc + sh;
    ((float4*)out)[i4] = r;
}

// ---------------------------------------------------------------- launch
extern "C" void kernel_launch(void* const* d_in, const int* in_sizes, int n_in,
                              void* d_out, int out_size, void* d_ws, size_t ws_size,
                              hipStream_t stream) {
    (void)in_sizes; (void)n_in; (void)out_size; (void)ws_size;
    const float* x   = (const float*)d_in[0];
    const float* dts = (const float*)d_in[1];
    const float* gw  = (const float*)d_in[2];
    const float* gb  = (const float*)d_in[3];
    const float* cwa = (const float*)d_in[4];
    const float* cwb = (const float*)d_in[5];
    const float* cba = (const float*)d_in[6];
    const float* cbb = (const float*)d_in[7];
    const float* gnw = (const float*)d_in[8];
    const float* gnb = (const float*)d_in[9];
    float* out = (float*)d_out;
    char* ws = (char*)d_ws;

    float2* S     = (float2*)ws;                        // 69,206,016 B
    float*  H1    = (float*)(ws + 69206016);            // 67,108,864 B
    float*  stats = (float*)(ws + 136314880);
    float2* A     = (float2*)(ws + 136331264);
    float2* Xt    = (float2*)(ws + 136364032);
    float2* gs    = (float2*)(ws + 136396800);
    // Wb lives in the S region (S is dead between irfft2 and the post-conv rfft2)
    unsigned short* Wb = (unsigned short*)ws;           // 294,912 B

    k_stats<<<4096, 256, 0, stream>>>(x, stats);
    k_params<<<16, 256, 0, stream>>>(stats, gw, gb, dts, A, Xt);
    k_rfft2<<<4096, 256, 0, stream>>>(x, S, Xt, 1);
    k_scan<<<2112, 256, 0, stream>>>(S, A);
    k_irfft2<<<4096, 256, 0, stream>>>(S, H1);
    k_wprep<<<576, 256, 0, stream>>>(cwa, cwb, Wb);     // after irfft2: S region now scratch
    k_conv_mfma<<<dim3(32, 32), 256, 0, stream>>>(H1, Wb, cba, cbb, out);
    k_rfft2<<<4096, 256, 0, stream>>>(out, S, Xt, 0);
    k_project<<<16896, 256, 0, stream>>>(S);
    k_irfft2<<<4096, 256, 0, stream>>>(S, H1);
    k_gnstats<<<128, 1024, 0, stream>>>(H1, gs);
    k_gnapply<<<16384, 256, 0, stream>>>(H1, gs, gnw, gnb, out);
}

// Round 4
// 329.927 us; speedup vs baseline: 4.8254x; 3.3632x over previous
//
#include <hip/hip_runtime.h>
#include <math.h>

#define PI_F 3.14159265358979323846f

typedef __attribute__((ext_vector_type(8))) short short8;
typedef __attribute__((ext_vector_type(4))) float f32x4;

static __device__ __forceinline__ unsigned short f2bf(float x) {
    unsigned u = __float_as_uint(x);
    unsigned r = (u + 0x7FFF + ((u >> 16) & 1)) >> 16;
    return (unsigned short)r;
}

static __device__ __forceinline__ float2 cadd(float2 a, float2 b) { return make_float2(a.x + b.x, a.y + b.y); }
static __device__ __forceinline__ float2 csub(float2 a, float2 b) { return make_float2(a.x - b.x, a.y - b.y); }
static __device__ __forceinline__ float2 cmul(float2 a, float2 b) { return make_float2(a.x * b.x - a.y * b.y, a.x * b.y + a.y * b.x); }
// a * conj(b)
static __device__ __forceinline__ float2 cmulc(float2 a, float2 b) { return make_float2(a.x * b.x + a.y * b.y, a.y * b.x - a.x * b.y); }

// DFT-8 in registers. S = -1: forward (e^{-i}), S = +1: inverse kernel (e^{+i}), unnormalized.
template <int S>
static __device__ __forceinline__ void dft8(float2* z) {
    const float RT = 0.70710678118654752440f;
    float2 ee0 = cadd(z[0], z[4]), ee1 = csub(z[0], z[4]);
    float2 eo0 = cadd(z[2], z[6]), eo1 = csub(z[2], z[6]);
    float2 oe0 = cadd(z[1], z[5]), oe1 = csub(z[1], z[5]);
    float2 oo0 = cadd(z[3], z[7]), oo1 = csub(z[3], z[7]);
    float2 ieo1 = make_float2(-S * eo1.y, S * eo1.x);
    float2 ioo1 = make_float2(-S * oo1.y, S * oo1.x);
    float2 E0 = cadd(ee0, eo0), E2 = csub(ee0, eo0);
    float2 E1 = cadd(ee1, ieo1), E3 = csub(ee1, ieo1);
    float2 O0 = cadd(oe0, oo0), O2 = csub(oe0, oo0);
    float2 O1 = cadd(oe1, ioo1), O3 = csub(oe1, ioo1);
    float2 w1O1 = make_float2(RT * (O1.x - S * O1.y), RT * (S * O1.x + O1.y));
    float2 w3O3 = make_float2(RT * (-O3.x - S * O3.y), RT * (S * O3.x - O3.y));
    float2 iO2  = make_float2(-S * O2.y, S * O2.x);
    z[0] = cadd(E0, O0);   z[4] = csub(E0, O0);
    z[1] = cadd(E1, w1O1); z[5] = csub(E1, w1O1);
    z[2] = cadd(E2, iO2);  z[6] = csub(E2, iO2);
    z[3] = cadd(E3, w3O3); z[7] = csub(E3, w3O3);
}

// ---------------------------------------------------------------- k_stats
__global__ __launch_bounds__(256) void k_stats(const float* __restrict__ x,
                                               float* __restrict__ stats) {
    int img = blockIdx.x;
    const float* p = x + (size_t)img * 4096;
    float s = 0.f;
    for (int i = threadIdx.x; i < 1024; i += 256) {
        float4 v = ((const float4*)p)[i];
        s += v.x + v.y + v.z + v.w;
    }
    __shared__ float red[256];
    red[threadIdx.x] = s;
    __syncthreads();
    for (int off = 128; off > 0; off >>= 1) {
        if (threadIdx.x < off) red[threadIdx.x] += red[threadIdx.x + off];
        __syncthreads();
    }
    if (threadIdx.x == 0) stats[img] = red[0] * (1.0f / 4096.0f);
}

// ---------------------------------------------------------------- k_params
__global__ __launch_bounds__(256) void k_params(const float* __restrict__ stats,
                                                const float* __restrict__ gw,
                                                const float* __restrict__ gb,
                                                const float* __restrict__ dts,
                                                float2* __restrict__ A,
                                                float2* __restrict__ Xt) {
    int idx = blockIdx.x * 256 + threadIdx.x;
    int c = idx & 127;
    int bt = idx >> 7;
    const float* st = stats + bt * 128;
    float nu = gb[c], om = gb[c + 128];
    for (int k = 0; k < 128; ++k) {
        float s = st[k];
        nu += s * gw[k * 256 + c];
        om += s * gw[k * 256 + c + 128];
    }
    float dt = dts[bt];
    float lre = -fabsf(nu);
    float lim = om;
    float mag = sqrtf(lre * lre + lim * lim);
    float er = expf(lre * dt);
    float sn, cs;
    sincosf(lim * dt, &sn, &cs);
    float2 Av = make_float2(er * cs, er * sn);
    float2 X;
    if (mag < 1e-6f) {
        X = make_float2(dt, 0.f);
    } else {
        float ar = Av.x - 1.f, ai = Av.y;
        float inv = 1.f / (mag * mag);
        X = make_float2((ar * lre + ai * lim) * inv, (ai * lre - ar * lim) * inv);
    }
    A[idx] = Av;
    Xt[idx] = X;
}

// ---------------------------------------------------------------- k_rfft2 (radix-8)
// Per-image 64x64 rfft2 (ortho), fused Xterm multiply. Out: S[img][ky=64][kx=33] float2.
__global__ __launch_bounds__(256) void k_rfft2(const float* __restrict__ xin,
                                               float2* __restrict__ Sout,
                                               const float2* __restrict__ Xterm,
                                               int use_xterm) {
    int img = blockIdx.x, tid = threadIdx.x;
    __shared__ float2 bufA[2178], bufB[2178], bufC[2176], twl[64];
    float* Af = (float*)bufA;
    if (tid < 64) {
        float sn, cs;
        sincosf(-(2.0f * PI_F / 64.0f) * (float)tid, &sn, &cs);
        twl[tid] = make_float2(cs, sn);
    }
    const float* xp = xin + (size_t)img * 4096;
    for (int i4 = tid; i4 < 1024; i4 += 256) {
        float4 v = ((const float4*)xp)[i4];
        int r = i4 >> 4, w = (i4 & 15) << 2;
        float* d = Af + r * 65 + w;
        d[0] = v.x; d[1] = v.y; d[2] = v.z; d[3] = v.w;
    }
    __syncthreads();

    // P2: row FFT stage A. z = row(2j) + i*row(2j+1) packed, DFT8 over a (n=8a+b), twiddle.
    {
        int j = tid >> 3, b = tid & 7;
        const float* p0 = Af + (2 * j) * 65 + b;
        const float* p1 = p0 + 65;
        float2 z[8];
#pragma unroll
        for (int a = 0; a < 8; ++a) z[a] = make_float2(p0[8 * a], p1[8 * a]);
        dft8<-1>(z);
#pragma unroll
        for (int c = 0; c < 8; ++c) bufB[j * 66 + c * 8 + b] = cmul(z[c], twl[(b * c) & 63]);
    }
    __syncthreads();

    // P3: row FFT stage B. DFT8 over b -> Z[k=c+8d].
    {
        int j = tid >> 3, c = tid & 7;
        float2 z[8];
#pragma unroll
        for (int b = 0; b < 8; ++b) z[b] = bufB[j * 66 + c * 8 + b];
        dft8<-1>(z);
#pragma unroll
        for (int d = 0; d < 8; ++d) bufC[j * 66 + c + 8 * d] = z[d];
    }
    __syncthreads();

    // P4: Hermitian unpack -> R[r][kx], stored transposed A[kx][r] (stride 66).
    for (int idx = tid; idx < 1056; idx += 256) {
        int j = idx / 33, k = idx - j * 33;
        float2 zk = bufC[j * 66 + k];
        float2 zm = bufC[j * 66 + ((64 - k) & 63)];
        bufA[k * 66 + 2 * j]     = make_float2((zk.x + zm.x) * 0.5f, (zk.y - zm.y) * 0.5f);
        bufA[k * 66 + 2 * j + 1] = make_float2((zk.y + zm.y) * 0.5f, (zm.x - zk.x) * 0.5f);
    }
    __syncthreads();

    // P5: column FFT stage A (complex, over r).
    auto colA = [&](int kx, int b) {
        float2 z[8];
#pragma unroll
        for (int a = 0; a < 8; ++a) z[a] = bufA[kx * 66 + 8 * a + b];
        dft8<-1>(z);
#pragma unroll
        for (int c = 0; c < 8; ++c) bufB[kx * 66 + c * 8 + b] = cmul(z[c], twl[(b * c) & 63]);
    };
    colA(tid >> 3, tid & 7);
    if (tid < 8) colA(32, tid);
    __syncthreads();

    // P6: column FFT stage B -> F[ky=c+8d][kx] into C[ky*34+kx].
    auto colB = [&](int kx, int c) {
        float2 z[8];
#pragma unroll
        for (int b = 0; b < 8; ++b) z[b] = bufB[kx * 66 + c * 8 + b];
        dft8<-1>(z);
#pragma unroll
        for (int d = 0; d < 8; ++d) bufC[(c + 8 * d) * 34 + kx] = z[d];
    };
    colB(tid >> 3, tid & 7);
    if (tid < 8) colB(32, tid);
    __syncthreads();

    // P7: ortho scale + Xterm, coalesced store.
    float2 xt = make_float2(1.f, 0.f);
    if (use_xterm) xt = Xterm[img];
    float2* op = Sout + (size_t)img * 2112;
    for (int i = tid; i < 2112; i += 256) {
        int ky = i / 33, kx = i - ky * 33;
        float2 v = bufC[ky * 34 + kx];
        float vr = v.x * (1.0f / 64.0f), vi = v.y * (1.0f / 64.0f);
        op[i] = make_float2(vr * xt.x - vi * xt.y, vr * xt.y + vi * xt.x);
    }
}

// ---------------------------------------------------------------- k_scan
__global__ __launch_bounds__(256) void k_scan(float2* __restrict__ S,
                                              const float2* __restrict__ A) {
    int tid = blockIdx.x * 256 + threadIdx.x;
    int spec = tid % 2112;
    int c = (tid / 2112) & 127;
    int b = tid / (2112 * 128);
    float2 h = make_float2(0.f, 0.f);
    for (int t = 0; t < 16; ++t) {
        int bt = b * 16 + t;
        float2 a = A[bt * 128 + c];
        size_t off = ((size_t)(bt * 128 + c)) * 2112 + spec;
        float2 x = S[off];
        float hr = a.x * h.x - a.y * h.y + x.x;
        float hi = a.x * h.y + a.y * h.x + x.y;
        h = make_float2(hr, hi);
        S[off] = h;
    }
}

// ---------------------------------------------------------------- k_irfft2 (radix-8)
// Per-image inverse of rfft2 (ortho). In: S[img][ky=64][kx=33]. Out: real 64x64.
// NOTE: matches numpy irfft semantics — imag parts of kx=0 and kx=32 bins are
// discarded (h_fft after the scan is NOT Hermitian; keeping them leaks the
// partner row's error through the packed-ifft trick).
__global__ __launch_bounds__(256) void k_irfft2(const float2* __restrict__ Sin,
                                                float* __restrict__ xout) {
    int img = blockIdx.x, tid = threadIdx.x;
    __shared__ float2 bufA[2178], bufB[2178], bufC[2176], twl[64];
    float* Cf = (float*)bufC;
    if (tid < 64) {
        float sn, cs;
        sincosf(-(2.0f * PI_F / 64.0f) * (float)tid, &sn, &cs);
        twl[tid] = make_float2(cs, sn);
    }
    const float2* ip = Sin + (size_t)img * 2112;
    for (int i = tid; i < 2112; i += 256) {
        int ky = i / 33, kx = i - ky * 33;
        bufA[ky * 34 + kx] = ip[i];
    }
    __syncthreads();

    // P2: column inverse stage A (over ky).
    auto colA = [&](int kx, int b) {
        float2 z[8];
#pragma unroll
        for (int a = 0; a < 8; ++a) z[a] = bufA[(8 * a + b) * 34 + kx];
        dft8<1>(z);
#pragma unroll
        for (int c = 0; c < 8; ++c) bufB[kx * 66 + c * 8 + b] = cmulc(z[c], twl[(b * c) & 63]);
    };
    colA(tid >> 3, tid & 7);
    if (tid < 8) colA(32, tid);
    __syncthreads();

    // P3: column inverse stage B -> T[h=c+8d][kx] into C[h*34+kx].
    auto colB = [&](int kx, int c) {
        float2 z[8];
#pragma unroll
        for (int b = 0; b < 8; ++b) z[b] = bufB[kx * 66 + c * 8 + b];
        dft8<1>(z);
#pragma unroll
        for (int d = 0; d < 8; ++d) bufC[(c + 8 * d) * 34 + kx] = z[d];
    };
    colB(tid >> 3, tid & 7);
    if (tid < 8) colB(32, tid);
    __syncthreads();

    // P4: pack row pairs with Hermitian extension: Z_j[k] = T[2j][k] + i*T[2j+1][k].
    // irfft semantics: drop imag of DC (kx=0) and Nyquist (kx=32) bins.
    for (int idx = tid; idx < 2048; idx += 256) {
        int j = idx >> 6, k = idx & 63;
        int kk = (k <= 32) ? k : 64 - k;
        float2 t0 = bufC[(2 * j) * 34 + kk];
        float2 t1 = bufC[(2 * j + 1) * 34 + kk];
        if (kk == 0 || kk == 32) { t0.y = 0.f; t1.y = 0.f; }   // <-- the fix
        float sgn = (k <= 32) ? 1.f : -1.f;
        t0.y *= sgn; t1.y *= sgn;
        bufA[j * 66 + k] = make_float2(t0.x - t1.y, t0.y + t1.x);
    }
    __syncthreads();

    // P5: row inverse stage A.
    {
        int j = tid >> 3, b = tid & 7;
        float2 z[8];
#pragma unroll
        for (int a = 0; a < 8; ++a) z[a] = bufA[j * 66 + 8 * a + b];
        dft8<1>(z);
#pragma unroll
        for (int c = 0; c < 8; ++c) bufB[j * 66 + c * 8 + b] = cmulc(z[c], twl[(b * c) & 63]);
    }
    __syncthreads();

    // P6: row inverse stage B -> real rows 2j, 2j+1.
    {
        int j = tid >> 3, c = tid & 7;
        float2 z[8];
#pragma unroll
        for (int b = 0; b < 8; ++b) z[b] = bufB[j * 66 + c * 8 + b];
        dft8<1>(z);
#pragma unroll
        for (int d = 0; d < 8; ++d) {
            int w = c + 8 * d;
            Cf[(2 * j) * 65 + w]     = z[d].x;
            Cf[(2 * j + 1) * 65 + w] = z[d].y;
        }
    }
    __syncthreads();

    float* op = xout + (size_t)img * 4096;
    for (int i4 = tid; i4 < 1024; i4 += 256) {
        int r = i4 >> 4, w = (i4 & 15) << 2;
        const float* s = Cf + r * 65 + w;
        ((float4*)op)[i4] = make_float4(s[0] * (1.0f / 64.0f), s[1] * (1.0f / 64.0f),
                                        s[2] * (1.0f / 64.0f), s[3] * (1.0f / 64.0f));
    }
}

// ---------------------------------------------------------------- k_wprep
__global__ __launch_bounds__(256) void k_wprep(const float* __restrict__ cwa,
                                               const float* __restrict__ cwb,
                                               unsigned short* __restrict__ Wb) {
    int idx = blockIdx.x * 256 + threadIdx.x;   // 147456 total
    int kl = idx & 31;
    int m = (idx >> 5) & 127;
    int tcb = idx >> 12;          // 0..35
    int cb = tcb & 3, t = tcb >> 2;
    int ci = cb * 32 + kl;
    int mm = m & 63, cc = ci & 63;
    float w;
    if (m < 64) w = (ci < 64) ? cwa[(mm * 64 + cc) * 9 + t] : -cwb[(mm * 64 + cc) * 9 + t];
    else        w = (ci < 64) ? cwb[(mm * 64 + cc) * 9 + t] :  cwa[(mm * 64 + cc) * 9 + t];
    if (m == ci && t == 4) w += 1.0f;   // residual folded into center tap
    Wb[idx] = f2bf(w);
}

// ---------------------------------------------------------------- k_conv_mfma
__global__ __launch_bounds__(256, 2) void k_conv_mfma(const float* __restrict__ hin,
                                                      const unsigned short* __restrict__ Wb,
                                                      const float* __restrict__ cba,
                                                      const float* __restrict__ cbb,
                                                      float* __restrict__ uout) {
    __shared__ __align__(16) char smem[65536];
    int f = blockIdx.y;
    int r0 = blockIdx.x * 2;
    int tid = threadIdx.x;
    const float* base = hin + (size_t)f * 524288;

    for (int j = tid; j < 4096; j += 256) {
        int row = j >> 10;
        int cig = (j >> 6) & 15;
        int col = j & 63;
        int gr = r0 - 1 + row;
        short8 v = (short8)0;
        if ((unsigned)gr < 64u) {
            const float* p = base + (size_t)(cig * 8) * 4096 + gr * 64 + col;
#pragma unroll
            for (int e = 0; e < 8; ++e) v[e] = (short)f2bf(p[(size_t)e * 4096]);
        }
        int byteoff = ((row * 64 + col) << 8) + ((cig ^ (col & 15)) << 4);
        *(short8*)(smem + byteoff) = v;
    }
    __syncthreads();

    int wid = tid >> 6, lane = tid & 63;
    int lhi = lane >> 4, llo = lane & 15;
    int row_off = wid & 1;
    int mbase = (wid >> 1) * 64;

    f32x4 acc[4][4];
#pragma unroll
    for (int mf = 0; mf < 4; ++mf)
#pragma unroll
        for (int nf = 0; nf < 4; ++nf) acc[mf][nf] = (f32x4)0.f;

    for (int t = 0; t < 9; ++t) {
        int dy = t / 3 - 1, dx = t % 3 - 1;
        int prow = row_off + 1 + dy;
#pragma unroll
        for (int cb = 0; cb < 4; ++cb) {
            short8 a[4];
            const unsigned short* wp = Wb + ((size_t)((t * 4 + cb) * 128 + mbase + llo)) * 32 + lhi * 8;
#pragma unroll
            for (int mf = 0; mf < 4; ++mf) a[mf] = *(const short8*)(wp + mf * 16 * 32);
            short8 b[4];
            int slot = cb * 4 + lhi;
#pragma unroll
            for (int nf = 0; nf < 4; ++nf) {
                int c = nf * 16 + llo;
                int cdx = c + dx;
                bool valid = ((unsigned)cdx < 64u);
                int cr = valid ? cdx : c;
                int byteoff = ((prow * 64 + cr) << 8) + ((slot ^ (cr & 15)) << 4);
                short8 bb = *(const short8*)(smem + byteoff);
                b[nf] = valid ? bb : (short8)0;
            }
#pragma unroll
            for (int mf = 0; mf < 4; ++mf)
#pragma unroll
                for (int nf = 0; nf < 4; ++nf)
                    acc[mf][nf] = __builtin_amdgcn_mfma_f32_16x16x32_bf16(a[mf], b[nf], acc[mf][nf], 0, 0, 0);
        }
    }

    int grow = r0 + row_off;
#pragma unroll
    for (int mf = 0; mf < 4; ++mf) {
#pragma unroll
        for (int r = 0; r < 4; ++r) {
            int co = mbase + mf * 16 + lhi * 4 + r;
            float bias = (co < 64) ? cba[co] : cbb[co - 64];
            float* op = uout + ((size_t)f * 128 + co) * 4096 + (size_t)grow * 64;
#pragma unroll
            for (int nf = 0; nf < 4; ++nf)
                op[nf * 16 + llo] = acc[mf][nf][r] + bias;
        }
    }
}

// ---------------------------------------------------------------- k_project
__global__ __launch_bounds__(256) void k_project(float2* __restrict__ S) {
    int tid = blockIdx.x * 256 + threadIdx.x;
    int spec = tid % 2112;
    int rest = tid / 2112;
    int ch = rest & 63;
    int f = rest >> 6;
    int kyi = spec / 33;
    int kxi = spec - kyi * 33;
    float kx = (float)kxi * (1.0f / 64.0f);
    float kyv = (float)(kyi < 32 ? kyi : kyi - 64) * (1.0f / 64.0f);
    float k2 = kx * kx + kyv * kyv;
    if (k2 > 0.f) {
        size_t ix = ((size_t)(f * 128 + ch)) * 2112 + spec;
        size_t iy = ((size_t)(f * 128 + 64 + ch)) * 2112 + spec;
        float2 vx = S[ix], vy = S[iy];
        float inv = 1.0f / k2;
        float pr = (kx * vx.x + kyv * vy.x) * inv;
        float pi = (kx * vx.y + kyv * vy.y) * inv;
        S[ix] = make_float2(vx.x - kx * pr, vx.y - kx * pi);
        S[iy] = make_float2(vy.x - kyv * pr, vy.y - kyv * pi);
    }
}

// ---------------------------------------------------------------- group norm
__global__ __launch_bounds__(1024) void k_gnstats(const float* __restrict__ u,
                                                  float2* __restrict__ gs) {
    int f = blockIdx.x >> 2, g = blockIdx.x & 3;
    const float* p = u + ((size_t)f * 128 + g * 32) * 4096;
    float s = 0.f, s2 = 0.f;
    for (int i = threadIdx.x; i < 32768; i += 1024) {
        float4 v = ((const float4*)p)[i];
        s += v.x + v.y + v.z + v.w;
        s2 += v.x * v.x + v.y * v.y + v.z * v.z + v.w * v.w;
    }
    __shared__ float rs[1024], rq[1024];
    rs[threadIdx.x] = s; rq[threadIdx.x] = s2;
    __syncthreads();
    for (int off = 512; off > 0; off >>= 1) {
        if (threadIdx.x < off) {
            rs[threadIdx.x] += rs[threadIdx.x + off];
            rq[threadIdx.x] += rq[threadIdx.x + off];
        }
        __syncthreads();
    }
    if (threadIdx.x == 0) {
        float mu = rs[0] * (1.0f / 131072.0f);
        float var = rq[0] * (1.0f / 131072.0f) - mu * mu;
        gs[blockIdx.x] = make_float2(mu, rsqrtf(var + 1e-5f));
    }
}

__global__ __launch_bounds__(256) void k_gnapply(const float* __restrict__ u,
                                                 const float2* __restrict__ gs,
                                                 const float* __restrict__ gnw,
                                                 const float* __restrict__ gnb,
                                                 float* __restrict__ out) {
    size_t i4 = (size_t)blockIdx.x * 256 + threadIdx.x;
    size_t i = i4 * 4;
    float4 v = ((const float4*)u)[i4];
    int cl = (int)(i >> 12);
    int c = cl & 127;
    int fg = cl >> 5;
    float2 ms = gs[fg];
    float sc = ms.y * gnw[c];
    float sh = gnb[c] - ms.x * sc;
    float4 r;
    r.x = v.x * sc + sh; r.y = v.y * sc + sh;
    r.z = v.z * sc + sh; r.w = v.w * sc + sh;
    ((float4*)out)[i4] = r;
}

// ---------------------------------------------------------------- launch
extern "C" void kernel_launch(void* const* d_in, const int* in_sizes, int n_in,
                              void* d_out, int out_size, void* d_ws, size_t ws_size,
                              hipStream_t stream) {
    (void)in_sizes; (void)n_in; (void)out_size; (void)ws_size;
    const float* x   = (const float*)d_in[0];
    const float* dts = (const float*)d_in[1];
    const float* gw  = (const float*)d_in[2];
    const float* gb  = (const float*)d_in[3];
    const float* cwa = (const float*)d_in[4];
    const float* cwb = (const float*)d_in[5];
    const float* cba = (const float*)d_in[6];
    const float* cbb = (const float*)d_in[7];
    const float* gnw = (const float*)d_in[8];
    const float* gnb = (const float*)d_in[9];
    float* out = (float*)d_out;
    char* ws = (char*)d_ws;

    float2* S     = (float2*)ws;                        // 69,206,016 B
    float*  H1    = (float*)(ws + 69206016);            // 67,108,864 B
    float*  stats = (float*)(ws + 136314880);
    float2* A     = (float2*)(ws + 136331264);
    float2* Xt    = (float2*)(ws + 136364032);
    float2* gs    = (float2*)(ws + 136396800);
    unsigned short* Wb = (unsigned short*)ws;           // aliases S (dead there)

    k_stats<<<4096, 256, 0, stream>>>(x, stats);
    k_params<<<16, 256, 0, stream>>>(stats, gw, gb, dts, A, Xt);
    k_rfft2<<<4096, 256, 0, stream>>>(x, S, Xt, 1);
    k_scan<<<2112, 256, 0, stream>>>(S, A);
    k_irfft2<<<4096, 256, 0, stream>>>(S, H1);
    k_wprep<<<576, 256, 0, stream>>>(cwa, cwb, Wb);
    k_conv_mfma<<<dim3(32, 32), 256, 0, stream>>>(H1, Wb, cba, cbb, out);
    k_rfft2<<<4096, 256, 0, stream>>>(out, S, Xt, 0);
    k_project<<<16896, 256, 0, stream>>>(S);
    k_irfft2<<<4096, 256, 0, stream>>>(S, H1);
    k_gnstats<<<128, 1024, 0, stream>>>(H1, gs);
    k_gnapply<<<16384, 256, 0, stream>>>(H1, gs, gnw, gnb, out);
}

// Round 5
// 271.300 us; speedup vs baseline: 5.8681x; 1.2161x over previous
//
#include <hip/hip_runtime.h>
#include <math.h>

#define PI_F 3.14159265358979323846f

typedef __attribute__((ext_vector_type(8))) short short8;
typedef __attribute__((ext_vector_type(4))) float f32x4;
typedef __attribute__((ext_vector_type(4))) unsigned short u16x4;

static __device__ __forceinline__ unsigned short f2bf(float x) {
    unsigned u = __float_as_uint(x);
    unsigned r = (u + 0x7FFF + ((u >> 16) & 1)) >> 16;
    return (unsigned short)r;
}

static __device__ __forceinline__ float2 cadd(float2 a, float2 b) { return make_float2(a.x + b.x, a.y + b.y); }
static __device__ __forceinline__ float2 csub(float2 a, float2 b) { return make_float2(a.x - b.x, a.y - b.y); }
static __device__ __forceinline__ float2 cmul(float2 a, float2 b) { return make_float2(a.x * b.x - a.y * b.y, a.x * b.y + a.y * b.x); }
// a * conj(b)
static __device__ __forceinline__ float2 cmulc(float2 a, float2 b) { return make_float2(a.x * b.x + a.y * b.y, a.y * b.x - a.x * b.y); }

// DFT-8 in registers. S = -1: forward, S = +1: inverse kernel (unnormalized).
template <int S>
static __device__ __forceinline__ void dft8(float2* z) {
    const float RT = 0.70710678118654752440f;
    float2 ee0 = cadd(z[0], z[4]), ee1 = csub(z[0], z[4]);
    float2 eo0 = cadd(z[2], z[6]), eo1 = csub(z[2], z[6]);
    float2 oe0 = cadd(z[1], z[5]), oe1 = csub(z[1], z[5]);
    float2 oo0 = cadd(z[3], z[7]), oo1 = csub(z[3], z[7]);
    float2 ieo1 = make_float2(-S * eo1.y, S * eo1.x);
    float2 ioo1 = make_float2(-S * oo1.y, S * oo1.x);
    float2 E0 = cadd(ee0, eo0), E2 = csub(ee0, eo0);
    float2 E1 = cadd(ee1, ieo1), E3 = csub(ee1, ieo1);
    float2 O0 = cadd(oe0, oo0), O2 = csub(oe0, oo0);
    float2 O1 = cadd(oe1, ioo1), O3 = csub(oe1, ioo1);
    float2 w1O1 = make_float2(RT * (O1.x - S * O1.y), RT * (S * O1.x + O1.y));
    float2 w3O3 = make_float2(RT * (-O3.x - S * O3.y), RT * (S * O3.x - O3.y));
    float2 iO2  = make_float2(-S * O2.y, S * O2.x);
    z[0] = cadd(E0, O0);   z[4] = csub(E0, O0);
    z[1] = cadd(E1, w1O1); z[5] = csub(E1, w1O1);
    z[2] = cadd(E2, iO2);  z[6] = csub(E2, iO2);
    z[3] = cadd(E3, w3O3); z[7] = csub(E3, w3O3);
}

// ---------------------------------------------------------------- k_params
__global__ __launch_bounds__(256) void k_params(const float* __restrict__ stats,
                                                const float* __restrict__ gw,
                                                const float* __restrict__ gb,
                                                const float* __restrict__ dts,
                                                float2* __restrict__ A,
                                                float2* __restrict__ Xt) {
    int idx = blockIdx.x * 256 + threadIdx.x;
    int c = idx & 127;
    int bt = idx >> 7;
    const float* st = stats + bt * 128;
    float nu = gb[c], om = gb[c + 128];
    for (int k = 0; k < 128; ++k) {
        float s = st[k];
        nu += s * gw[k * 256 + c];
        om += s * gw[k * 256 + c + 128];
    }
    float dt = dts[bt];
    float lre = -fabsf(nu);
    float lim = om;
    float mag = sqrtf(lre * lre + lim * lim);
    float er = expf(lre * dt);
    float sn, cs;
    sincosf(lim * dt, &sn, &cs);
    float2 Av = make_float2(er * cs, er * sn);
    float2 X;
    if (mag < 1e-6f) {
        X = make_float2(dt, 0.f);
    } else {
        float ar = Av.x - 1.f, ai = Av.y;
        float inv = 1.f / (mag * mag);
        X = make_float2((ar * lre + ai * lim) * inv, (ai * lre - ar * lim) * inv);
    }
    A[idx] = Av;
    Xt[idx] = X;
}

// ---------------------------------------------------------------- k_rfft2s (radix-8, fused stats)
// Per-image 64x64 rfft2 (ortho). Also emits stats[img] = mean(image).
__global__ __launch_bounds__(256) void k_rfft2s(const float* __restrict__ xin,
                                                float2* __restrict__ Sout,
                                                float* __restrict__ stats) {
    int img = blockIdx.x, tid = threadIdx.x;
    __shared__ float2 bufA[2178], bufB[2178], bufC[2176], twl[64];
    __shared__ float red[4];
    float* Af = (float*)bufA;
    if (tid < 64) {
        float sn, cs;
        sincosf(-(2.0f * PI_F / 64.0f) * (float)tid, &sn, &cs);
        twl[tid] = make_float2(cs, sn);
    }
    const float* xp = xin + (size_t)img * 4096;
    float ssum = 0.f;
    for (int i4 = tid; i4 < 1024; i4 += 256) {
        float4 v = ((const float4*)xp)[i4];
        ssum += v.x + v.y + v.z + v.w;
        int r = i4 >> 4, w = (i4 & 15) << 2;
        float* d = Af + r * 65 + w;
        d[0] = v.x; d[1] = v.y; d[2] = v.z; d[3] = v.w;
    }
    // wave reduce (no extra barrier beyond the load barrier)
    for (int off = 32; off > 0; off >>= 1) ssum += __shfl_xor(ssum, off, 64);
    if ((tid & 63) == 0) red[tid >> 6] = ssum;
    __syncthreads();
    if (tid == 0) stats[img] = (red[0] + red[1] + red[2] + red[3]) * (1.0f / 4096.0f);

    // P2: row FFT stage A (rows packed in pairs).
    {
        int j = tid >> 3, b = tid & 7;
        const float* p0 = Af + (2 * j) * 65 + b;
        const float* p1 = p0 + 65;
        float2 z[8];
#pragma unroll
        for (int a = 0; a < 8; ++a) z[a] = make_float2(p0[8 * a], p1[8 * a]);
        dft8<-1>(z);
#pragma unroll
        for (int c = 0; c < 8; ++c) bufB[j * 66 + c * 8 + b] = cmul(z[c], twl[(b * c) & 63]);
    }
    __syncthreads();

    // P3: row FFT stage B.
    {
        int j = tid >> 3, c = tid & 7;
        float2 z[8];
#pragma unroll
        for (int b = 0; b < 8; ++b) z[b] = bufB[j * 66 + c * 8 + b];
        dft8<-1>(z);
#pragma unroll
        for (int d = 0; d < 8; ++d) bufC[j * 66 + c + 8 * d] = z[d];
    }
    __syncthreads();

    // P4: Hermitian unpack -> transposed.
    for (int idx = tid; idx < 1056; idx += 256) {
        int j = idx / 33, k = idx - j * 33;
        float2 zk = bufC[j * 66 + k];
        float2 zm = bufC[j * 66 + ((64 - k) & 63)];
        bufA[k * 66 + 2 * j]     = make_float2((zk.x + zm.x) * 0.5f, (zk.y - zm.y) * 0.5f);
        bufA[k * 66 + 2 * j + 1] = make_float2((zk.y + zm.y) * 0.5f, (zm.x - zk.x) * 0.5f);
    }
    __syncthreads();

    // P5: column FFT stage A.
    auto colA = [&](int kx, int b) {
        float2 z[8];
#pragma unroll
        for (int a = 0; a < 8; ++a) z[a] = bufA[kx * 66 + 8 * a + b];
        dft8<-1>(z);
#pragma unroll
        for (int c = 0; c < 8; ++c) bufB[kx * 66 + c * 8 + b] = cmul(z[c], twl[(b * c) & 63]);
    };
    colA(tid >> 3, tid & 7);
    if (tid < 8) colA(32, tid);
    __syncthreads();

    // P6: column FFT stage B -> C[ky*34+kx].
    auto colB = [&](int kx, int c) {
        float2 z[8];
#pragma unroll
        for (int b = 0; b < 8; ++b) z[b] = bufB[kx * 66 + c * 8 + b];
        dft8<-1>(z);
#pragma unroll
        for (int d = 0; d < 8; ++d) bufC[(c + 8 * d) * 34 + kx] = z[d];
    };
    colB(tid >> 3, tid & 7);
    if (tid < 8) colB(32, tid);
    __syncthreads();

    // P7: ortho scale, coalesced store.
    float2* op = Sout + (size_t)img * 2112;
    for (int i = tid; i < 2112; i += 256) {
        int ky = i / 33, kx = i - ky * 33;
        float2 v = bufC[ky * 34 + kx];
        op[i] = make_float2(v.x * (1.0f / 64.0f), v.y * (1.0f / 64.0f));
    }
}

// ---------------------------------------------------------------- k_scan (fused Xterm)
__global__ __launch_bounds__(256) void k_scan(float2* __restrict__ S,
                                              const float2* __restrict__ A,
                                              const float2* __restrict__ Xt) {
    int tid = blockIdx.x * 256 + threadIdx.x;
    int spec = tid % 2112;
    int c = (tid / 2112) & 127;
    int b = tid / (2112 * 128);
    float2 h = make_float2(0.f, 0.f);
    for (int t = 0; t < 16; ++t) {
        int bt = b * 16 + t;
        float2 a = A[bt * 128 + c];
        float2 xt = Xt[bt * 128 + c];
        size_t off = ((size_t)(bt * 128 + c)) * 2112 + spec;
        float2 xr = S[off];
        float2 x = cmul(xr, xt);
        float hr = a.x * h.x - a.y * h.y + x.x;
        float hi = a.x * h.y + a.y * h.x + x.y;
        h = make_float2(hr, hi);
        S[off] = h;
    }
}

// ---------------------------------------------------------------- k_irfft2b (radix-8, bf16 out)
// Inverse rfft2 (ortho) writing bf16 (conv input; residual folded into conv weights).
__global__ __launch_bounds__(256) void k_irfft2b(const float2* __restrict__ Sin,
                                                 unsigned short* __restrict__ hb) {
    int img = blockIdx.x, tid = threadIdx.x;
    __shared__ float2 bufA[2178], bufB[2178], bufC[2176], twl[64];
    float* Cf = (float*)bufC;
    if (tid < 64) {
        float sn, cs;
        sincosf(-(2.0f * PI_F / 64.0f) * (float)tid, &sn, &cs);
        twl[tid] = make_float2(cs, sn);
    }
    const float2* ip = Sin + (size_t)img * 2112;
    for (int i = tid; i < 2112; i += 256) {
        int ky = i / 33, kx = i - ky * 33;
        bufA[ky * 34 + kx] = ip[i];
    }
    __syncthreads();

    auto colA = [&](int kx, int b) {
        float2 z[8];
#pragma unroll
        for (int a = 0; a < 8; ++a) z[a] = bufA[(8 * a + b) * 34 + kx];
        dft8<1>(z);
#pragma unroll
        for (int c = 0; c < 8; ++c) bufB[kx * 66 + c * 8 + b] = cmulc(z[c], twl[(b * c) & 63]);
    };
    colA(tid >> 3, tid & 7);
    if (tid < 8) colA(32, tid);
    __syncthreads();

    auto colB = [&](int kx, int c) {
        float2 z[8];
#pragma unroll
        for (int b = 0; b < 8; ++b) z[b] = bufB[kx * 66 + c * 8 + b];
        dft8<1>(z);
#pragma unroll
        for (int d = 0; d < 8; ++d) bufC[(c + 8 * d) * 34 + kx] = z[d];
    };
    colB(tid >> 3, tid & 7);
    if (tid < 8) colB(32, tid);
    __syncthreads();

    // pack row pairs; irfft semantics: drop imag of DC/Nyquist kx bins.
    for (int idx = tid; idx < 2048; idx += 256) {
        int j = idx >> 6, k = idx & 63;
        int kk = (k <= 32) ? k : 64 - k;
        float2 t0 = bufC[(2 * j) * 34 + kk];
        float2 t1 = bufC[(2 * j + 1) * 34 + kk];
        if (kk == 0 || kk == 32) { t0.y = 0.f; t1.y = 0.f; }
        float sgn = (k <= 32) ? 1.f : -1.f;
        t0.y *= sgn; t1.y *= sgn;
        bufA[j * 66 + k] = make_float2(t0.x - t1.y, t0.y + t1.x);
    }
    __syncthreads();

    {
        int j = tid >> 3, b = tid & 7;
        float2 z[8];
#pragma unroll
        for (int a = 0; a < 8; ++a) z[a] = bufA[j * 66 + 8 * a + b];
        dft8<1>(z);
#pragma unroll
        for (int c = 0; c < 8; ++c) bufB[j * 66 + c * 8 + b] = cmulc(z[c], twl[(b * c) & 63]);
    }
    __syncthreads();

    {
        int j = tid >> 3, c = tid & 7;
        float2 z[8];
#pragma unroll
        for (int b = 0; b < 8; ++b) z[b] = bufB[j * 66 + c * 8 + b];
        dft8<1>(z);
#pragma unroll
        for (int d = 0; d < 8; ++d) {
            int w = c + 8 * d;
            Cf[(2 * j) * 65 + w]     = z[d].x;
            Cf[(2 * j + 1) * 65 + w] = z[d].y;
        }
    }
    __syncthreads();

    unsigned short* op = hb + (size_t)img * 4096;
    for (int i4 = tid; i4 < 1024; i4 += 256) {
        int r = i4 >> 4, w = (i4 & 15) << 2;
        const float* s = Cf + r * 65 + w;
        u16x4 o;
        o[0] = f2bf(s[0] * (1.0f / 64.0f));
        o[1] = f2bf(s[1] * (1.0f / 64.0f));
        o[2] = f2bf(s[2] * (1.0f / 64.0f));
        o[3] = f2bf(s[3] * (1.0f / 64.0f));
        ((u16x4*)op)[i4] = o;
    }
}

// ---------------------------------------------------------------- k_wprep
__global__ __launch_bounds__(256) void k_wprep(const float* __restrict__ cwa,
                                               const float* __restrict__ cwb,
                                               unsigned short* __restrict__ Wb) {
    int idx = blockIdx.x * 256 + threadIdx.x;   // 147456 total
    int kl = idx & 31;
    int m = (idx >> 5) & 127;
    int tcb = idx >> 12;          // 0..35
    int cb = tcb & 3, t = tcb >> 2;
    int ci = cb * 32 + kl;
    int mm = m & 63, cc = ci & 63;
    float w;
    if (m < 64) w = (ci < 64) ? cwa[(mm * 64 + cc) * 9 + t] : -cwb[(mm * 64 + cc) * 9 + t];
    else        w = (ci < 64) ? cwb[(mm * 64 + cc) * 9 + t] :  cwa[(mm * 64 + cc) * 9 + t];
    if (m == ci && t == 4) w += 1.0f;   // residual folded into center tap
    Wb[idx] = f2bf(w);
}

// ---------------------------------------------------------------- k_conv_mfma (bf16 input)
__global__ __launch_bounds__(256, 2) void k_conv_mfma(const unsigned short* __restrict__ hb,
                                                      const unsigned short* __restrict__ Wb,
                                                      const float* __restrict__ cba,
                                                      const float* __restrict__ cbb,
                                                      float* __restrict__ uout) {
    __shared__ __align__(16) char smem[65536];
    int f = blockIdx.y;
    int r0 = blockIdx.x * 2;
    int tid = threadIdx.x;
    const unsigned short* base = hb + (size_t)f * 524288;

    for (int j = tid; j < 4096; j += 256) {
        int row = j >> 10;
        int cig = (j >> 6) & 15;
        int col = j & 63;
        int gr = r0 - 1 + row;
        short8 v = (short8)0;
        if ((unsigned)gr < 64u) {
            const unsigned short* p = base + (size_t)(cig * 8) * 4096 + gr * 64 + col;
#pragma unroll
            for (int e = 0; e < 8; ++e) v[e] = (short)p[(size_t)e * 4096];
        }
        int byteoff = ((row * 64 + col) << 8) + ((cig ^ (col & 15)) << 4);
        *(short8*)(smem + byteoff) = v;
    }
    __syncthreads();

    int wid = tid >> 6, lane = tid & 63;
    int lhi = lane >> 4, llo = lane & 15;
    int row_off = wid & 1;
    int mbase = (wid >> 1) * 64;

    f32x4 acc[4][4];
#pragma unroll
    for (int mf = 0; mf < 4; ++mf)
#pragma unroll
        for (int nf = 0; nf < 4; ++nf) acc[mf][nf] = (f32x4)0.f;

    for (int t = 0; t < 9; ++t) {
        int dy = t / 3 - 1, dx = t % 3 - 1;
        int prow = row_off + 1 + dy;
#pragma unroll
        for (int cb = 0; cb < 4; ++cb) {
            short8 a[4];
            const unsigned short* wp = Wb + ((size_t)((t * 4 + cb) * 128 + mbase + llo)) * 32 + lhi * 8;
#pragma unroll
            for (int mf = 0; mf < 4; ++mf) a[mf] = *(const short8*)(wp + mf * 16 * 32);
            short8 b[4];
            int slot = cb * 4 + lhi;
#pragma unroll
            for (int nf = 0; nf < 4; ++nf) {
                int c = nf * 16 + llo;
                int cdx = c + dx;
                bool valid = ((unsigned)cdx < 64u);
                int cr = valid ? cdx : c;
                int byteoff = ((prow * 64 + cr) << 8) + ((slot ^ (cr & 15)) << 4);
                short8 bb = *(const short8*)(smem + byteoff);
                b[nf] = valid ? bb : (short8)0;
            }
#pragma unroll
            for (int mf = 0; mf < 4; ++mf)
#pragma unroll
                for (int nf = 0; nf < 4; ++nf)
                    acc[mf][nf] = __builtin_amdgcn_mfma_f32_16x16x32_bf16(a[mf], b[nf], acc[mf][nf], 0, 0, 0);
        }
    }

    int grow = r0 + row_off;
#pragma unroll
    for (int mf = 0; mf < 4; ++mf) {
#pragma unroll
        for (int r = 0; r < 4; ++r) {
            int co = mbase + mf * 16 + lhi * 4 + r;
            float bias = (co < 64) ? cba[co] : cbb[co - 64];
            float* op = uout + ((size_t)f * 128 + co) * 4096 + (size_t)grow * 64;
#pragma unroll
            for (int nf = 0; nf < 4; ++nf)
                op[nf * 16 + llo] = acc[mf][nf][r] + bias;
        }
    }
}

// ---------------------------------------------------------------- k_helm (fused rfft2 + project + irfft2 + GN partials)
// Block = (frame f, channel c in 0..63). Handles images (f, c) and (f, c+64).
__global__ __launch_bounds__(256) void k_helm(const float* __restrict__ uin,
                                              float* __restrict__ uo,
                                              float* __restrict__ partials) {
    int bid = blockIdx.x;
    int f = bid >> 6, c = bid & 63;
    int tid = threadIdx.x;
    __shared__ float2 W0[2178], W1[2178], SP[2178], twl[64];
    __shared__ float red[4];
    if (tid < 64) {
        float sn, cs;
        sincosf(-(2.0f * PI_F / 64.0f) * (float)tid, &sn, &cs);
        twl[tid] = make_float2(cs, sn);
    }

    // ---- phase lambdas (proven radix-8 building blocks) ----
    auto loadimg = [&](const float* xp, float2* W) {
        float* Wf = (float*)W;
        for (int i4 = tid; i4 < 1024; i4 += 256) {
            float4 v = ((const float4*)xp)[i4];
            int r = i4 >> 4, w = (i4 & 15) << 2;
            float* d = Wf + r * 65 + w;
            d[0] = v.x; d[1] = v.y; d[2] = v.z; d[3] = v.w;
        }
    };
    auto fwdP2 = [&](const float2* src, float2* dst) {
        const float* Af = (const float*)src;
        int j = tid >> 3, b = tid & 7;
        const float* p0 = Af + (2 * j) * 65 + b;
        const float* p1 = p0 + 65;
        float2 z[8];
#pragma unroll
        for (int a = 0; a < 8; ++a) z[a] = make_float2(p0[8 * a], p1[8 * a]);
        dft8<-1>(z);
#pragma unroll
        for (int cc = 0; cc < 8; ++cc) dst[j * 66 + cc * 8 + b] = cmul(z[cc], twl[(b * cc) & 63]);
    };
    auto fwdP3 = [&](const float2* src, float2* dst) {
        int j = tid >> 3, cc = tid & 7;
        float2 z[8];
#pragma unroll
        for (int b = 0; b < 8; ++b) z[b] = src[j * 66 + cc * 8 + b];
        dft8<-1>(z);
#pragma unroll
        for (int d = 0; d < 8; ++d) dst[j * 66 + cc + 8 * d] = z[d];
    };
    auto fwdP4 = [&](const float2* src, float2* dst) {
        for (int idx = tid; idx < 1056; idx += 256) {
            int j = idx / 33, k = idx - j * 33;
            float2 zk = src[j * 66 + k];
            float2 zm = src[j * 66 + ((64 - k) & 63)];
            dst[k * 66 + 2 * j]     = make_float2((zk.x + zm.x) * 0.5f, (zk.y - zm.y) * 0.5f);
            dst[k * 66 + 2 * j + 1] = make_float2((zk.y + zm.y) * 0.5f, (zm.x - zk.x) * 0.5f);
        }
    };
    auto fwdP5 = [&](const float2* src, float2* dst) {
        auto body = [&](int kx, int b) {
            float2 z[8];
#pragma unroll
            for (int a = 0; a < 8; ++a) z[a] = src[kx * 66 + 8 * a + b];
            dft8<-1>(z);
#pragma unroll
            for (int cc = 0; cc < 8; ++cc) dst[kx * 66 + cc * 8 + b] = cmul(z[cc], twl[(b * cc) & 63]);
        };
        body(tid >> 3, tid & 7);
        if (tid < 8) body(32, tid);
    };
    auto fwdP6 = [&](const float2* src, float2* dst) {
        auto body = [&](int kx, int cc) {
            float2 z[8];
#pragma unroll
            for (int b = 0; b < 8; ++b) z[b] = src[kx * 66 + cc * 8 + b];
            dft8<-1>(z);
#pragma unroll
            for (int d = 0; d < 8; ++d) dst[(cc + 8 * d) * 34 + kx] = z[d];
        };
        body(tid >> 3, tid & 7);
        if (tid < 8) body(32, tid);
    };
    auto invA = [&](const float2* src, float2* dst) {
        auto body = [&](int kx, int b) {
            float2 z[8];
#pragma unroll
            for (int a = 0; a < 8; ++a) z[a] = src[(8 * a + b) * 34 + kx];
            dft8<1>(z);
#pragma unroll
            for (int cc = 0; cc < 8; ++cc) dst[kx * 66 + cc * 8 + b] = cmulc(z[cc], twl[(b * cc) & 63]);
        };
        body(tid >> 3, tid & 7);
        if (tid < 8) body(32, tid);
    };
    auto invB = [&](const float2* src, float2* dst) {
        auto body = [&](int kx, int cc) {
            float2 z[8];
#pragma unroll
            for (int b = 0; b < 8; ++b) z[b] = src[kx * 66 + cc * 8 + b];
            dft8<1>(z);
#pragma unroll
            for (int d = 0; d < 8; ++d) dst[(cc + 8 * d) * 34 + kx] = z[d];
        };
        body(tid >> 3, tid & 7);
        if (tid < 8) body(32, tid);
    };
    auto invP4 = [&](const float2* src, float2* dst) {
        for (int idx = tid; idx < 2048; idx += 256) {
            int j = idx >> 6, k = idx & 63;
            int kk = (k <= 32) ? k : 64 - k;
            float2 t0 = src[(2 * j) * 34 + kk];
            float2 t1 = src[(2 * j + 1) * 34 + kk];
            if (kk == 0 || kk == 32) { t0.y = 0.f; t1.y = 0.f; }
            float sgn = (k <= 32) ? 1.f : -1.f;
            t0.y *= sgn; t1.y *= sgn;
            dst[j * 66 + k] = make_float2(t0.x - t1.y, t0.y + t1.x);
        }
    };
    auto invP5 = [&](const float2* src, float2* dst) {
        int j = tid >> 3, b = tid & 7;
        float2 z[8];
#pragma unroll
        for (int a = 0; a < 8; ++a) z[a] = src[j * 66 + 8 * a + b];
        dft8<1>(z);
#pragma unroll
        for (int cc = 0; cc < 8; ++cc) dst[j * 66 + cc * 8 + b] = cmulc(z[cc], twl[(b * cc) & 63]);
    };
    auto invP6 = [&](const float2* src, float2* dst) {
        float* Df = (float*)dst;
        int j = tid >> 3, cc = tid & 7;
        float2 z[8];
#pragma unroll
        for (int b = 0; b < 8; ++b) z[b] = src[j * 66 + cc * 8 + b];
        dft8<1>(z);
#pragma unroll
        for (int d = 0; d < 8; ++d) {
            int w = cc + 8 * d;
            Df[(2 * j) * 65 + w]     = z[d].x;
            Df[(2 * j + 1) * 65 + w] = z[d].y;
        }
    };
    // write real image (scaled 1/4096 = fwd 1/64 * inv 1/64) + GN partial sums
    auto writeimg = [&](const float2* W, float* op, int pslot) {
        const float* Wf = (const float*)W;
        float s = 0.f, q = 0.f;
        for (int i4 = tid; i4 < 1024; i4 += 256) {
            int r = i4 >> 4, w = (i4 & 15) << 2;
            const float* sp = Wf + r * 65 + w;
            float4 v = make_float4(sp[0] * (1.0f / 4096.0f), sp[1] * (1.0f / 4096.0f),
                                   sp[2] * (1.0f / 4096.0f), sp[3] * (1.0f / 4096.0f));
            s += v.x + v.y + v.z + v.w;
            q += v.x * v.x + v.y * v.y + v.z * v.z + v.w * v.w;
            ((float4*)op)[i4] = v;
        }
        for (int off = 32; off > 0; off >>= 1) {
            s += __shfl_xor(s, off, 64);
            q += __shfl_xor(q, off, 64);
        }
        __syncthreads();   // red[] reuse safety
        if ((tid & 63) == 0) { red[tid >> 6] = s; }
        __syncthreads();
        float stot = (tid == 0) ? (red[0] + red[1] + red[2] + red[3]) : 0.f;
        __syncthreads();
        if ((tid & 63) == 0) { red[tid >> 6] = q; }
        __syncthreads();
        if (tid == 0) {
            float qtot = red[0] + red[1] + red[2] + red[3];
            float* pp = partials + ((size_t)f * 64 + c) * 4 + pslot * 2;
            pp[0] = stot;
            pp[1] = qtot;
        }
    };

    const float* u0 = uin + ((size_t)f * 128 + c) * 4096;
    const float* u1 = uin + ((size_t)f * 128 + 64 + c) * 4096;
    float* o0 = uo + ((size_t)f * 128 + c) * 4096;
    float* o1 = uo + ((size_t)f * 128 + 64 + c) * 4096;

    // forward image0 -> SP
    loadimg(u0, W0);            __syncthreads();
    fwdP2(W0, W1);              __syncthreads();
    fwdP3(W1, W0);              __syncthreads();
    fwdP4(W0, W1);              __syncthreads();
    fwdP5(W1, W0);              __syncthreads();
    fwdP6(W0, SP);              __syncthreads();
    // forward image1 -> W1
    loadimg(u1, W0);            __syncthreads();
    fwdP2(W0, W1);              __syncthreads();
    fwdP3(W1, W0);              __syncthreads();
    fwdP4(W0, W1);              __syncthreads();
    fwdP5(W1, W0);              __syncthreads();
    fwdP6(W0, W1);              __syncthreads();

    // Helmholtz projection: SP = vx spectrum, W1 = vy spectrum (34-layout).
    for (int i = tid; i < 2176; i += 256) {
        int ky = i / 34, kx = i - ky * 34;
        if (kx > 32) continue;
        float kxv = (float)kx * (1.0f / 64.0f);
        float kyv = (float)(ky < 32 ? ky : ky - 64) * (1.0f / 64.0f);
        float k2 = kxv * kxv + kyv * kyv;
        if (k2 > 0.f) {
            float2 vx = SP[i], vy = W1[i];
            float inv = 1.0f / k2;
            float pr = (kxv * vx.x + kyv * vy.x) * inv;
            float pi = (kxv * vx.y + kyv * vy.y) * inv;
            SP[i] = make_float2(vx.x - kxv * pr, vx.y - kxv * pi);
            W1[i] = make_float2(vy.x - kyv * pr, vy.y - kyv * pi);
        }
    }
    __syncthreads();

    // inverse image0: SP -> real (scratch W0, SP)
    invA(SP, W0);               __syncthreads();
    invB(W0, SP);               __syncthreads();
    invP4(SP, W0);              __syncthreads();
    invP5(W0, SP);              __syncthreads();
    invP6(SP, W0);              __syncthreads();
    writeimg(W0, o0, 0);        __syncthreads();
    // inverse image1: W1 -> real (scratch W0, W1)
    invA(W1, W0);               __syncthreads();
    invB(W0, W1);               __syncthreads();
    invP4(W1, W0);              __syncthreads();
    invP5(W0, W1);              __syncthreads();
    invP6(W1, W0);              __syncthreads();
    writeimg(W0, o1, 1);
}

// ---------------------------------------------------------------- k_gnfin
__global__ __launch_bounds__(128) void k_gnfin(const float* __restrict__ partials,
                                               float2* __restrict__ gs) {
    int i = threadIdx.x;          // 0..127 = f*4 + g
    int f = i >> 2, g = i & 3;
    const float4* p4 = (const float4*)partials;
    float s = 0.f, q = 0.f;
    if (g < 2) {
        for (int cc = 0; cc < 32; ++cc) {
            float4 p = p4[f * 64 + g * 32 + cc];
            s += p.x; q += p.y;
        }
    } else {
        for (int cc = 0; cc < 32; ++cc) {
            float4 p = p4[f * 64 + (g - 2) * 32 + cc];
            s += p.z; q += p.w;
        }
    }
    float mu = s * (1.0f / 131072.0f);
    float var = q * (1.0f / 131072.0f) - mu * mu;
    gs[i] = make_float2(mu, rsqrtf(var + 1e-5f));
}

// ---------------------------------------------------------------- k_gnapply
__global__ __launch_bounds__(256) void k_gnapply(const float* __restrict__ u,
                                                 const float2* __restrict__ gs,
                                                 const float* __restrict__ gnw,
                                                 const float* __restrict__ gnb,
                                                 float* __restrict__ out) {
    size_t i4 = (size_t)blockIdx.x * 256 + threadIdx.x;
    size_t i = i4 * 4;
    float4 v = ((const float4*)u)[i4];
    int cl = (int)(i >> 12);
    int c = cl & 127;
    int fg = cl >> 5;
    float2 ms = gs[fg];
    float sc = ms.y * gnw[c];
    float sh = gnb[c] - ms.x * sc;
    float4 r;
    r.x = v.x * sc + sh; r.y = v.y * sc + sh;
    r.z = v.z * sc + sh; r.w = v.w * sc + sh;
    ((float4*)out)[i4] = r;
}

// ---------------------------------------------------------------- launch
extern "C" void kernel_launch(void* const* d_in, const int* in_sizes, int n_in,
                              void* d_out, int out_size, void* d_ws, size_t ws_size,
                              hipStream_t stream) {
    (void)in_sizes; (void)n_in; (void)out_size; (void)ws_size;
    const float* x   = (const float*)d_in[0];
    const float* dts = (const float*)d_in[1];
    const float* gw  = (const float*)d_in[2];
    const float* gb  = (const float*)d_in[3];
    const float* cwa = (const float*)d_in[4];
    const float* cwb = (const float*)d_in[5];
    const float* cba = (const float*)d_in[6];
    const float* cbb = (const float*)d_in[7];
    const float* gnw = (const float*)d_in[8];
    const float* gnb = (const float*)d_in[9];
    float* out = (float*)d_out;
    char* ws = (char*)d_ws;

    float2* S  = (float2*)ws;                           // 69,206,016 B  (steps 1-4)
    float*  H1 = (float*)(ws + 69206016);               // 67,108,864 B  (u, steps 7-9)
    // Hb (bf16 conv input) aliases H1's region: Hb live steps 4-6, H1 live 7-9.
    unsigned short* Hb = (unsigned short*)(ws + 69206016);   // 33,554,432 B
    float*  stats = (float*)(ws + 136314880);           // 16,384 B
    float2* A     = (float2*)(ws + 136331264);          // 32,768 B
    float2* Xt    = (float2*)(ws + 136364032);          // 32,768 B
    float2* gs    = (float2*)(ws + 136396800);          // 1,024 B
    float*  partials = (float*)(ws + 136397824);        // 32,768 B
    unsigned short* Wb = (unsigned short*)ws;           // aliases S (dead after irfft2b)

    k_rfft2s<<<4096, 256, 0, stream>>>(x, S, stats);
    k_params<<<16, 256, 0, stream>>>(stats, gw, gb, dts, A, Xt);
    k_scan<<<2112, 256, 0, stream>>>(S, A, Xt);
    k_irfft2b<<<4096, 256, 0, stream>>>(S, Hb);
    k_wprep<<<576, 256, 0, stream>>>(cwa, cwb, Wb);
    k_conv_mfma<<<dim3(32, 32), 256, 0, stream>>>(Hb, Wb, cba, cbb, out);
    k_helm<<<2048, 256, 0, stream>>>(out, H1, partials);
    k_gnfin<<<1, 128, 0, stream>>>(partials, gs);
    k_gnapply<<<16384, 256, 0, stream>>>(H1, gs, gnw, gnb, out);
}